// Round 1
// baseline (688.475 us; speedup 1.0000x reference)
//
#include <hip/hip_runtime.h>

// ---------------------------------------------------------------------------
// PatternEncoder: 2x GCNConv -> global_mean_pool -> 5-layer MLP
// N=50000 nodes, E=800000 edges, D=128, G=256 graphs, H=1024
//
// GCNConv(x,W,b) = relu( D^-1/2 (A+I) D^-1/2 x W + b )
// Layer 1: aggregate first (128 wide), then GEMM 128->256.
// Layer 2: GEMM 256->128 (row-scaled by dinv), then aggregate + bias + relu.
// Aggregation is pull-based via CSR (no float atomics).
// ---------------------------------------------------------------------------

__global__ void count_deg_kernel(const int* __restrict__ col, int E,
                                 int* __restrict__ indeg) {
    int i = blockIdx.x * blockDim.x + threadIdx.x;
    if (i < E) atomicAdd(&indeg[col[i]], 1);
}

// single-block exclusive scan: thread-local chunk + Hillis-Steele over 1024 partials
__global__ void scan_kernel(const int* __restrict__ indeg, int* __restrict__ offs,
                            int N) {
    __shared__ int sm[1024];
    int tid = threadIdx.x;
    int chunk = (N + 1023) / 1024;
    int s = tid * chunk;
    int e = s + chunk; if (e > N) e = N; if (s > N) s = N;
    int sum = 0;
    for (int i = s; i < e; ++i) sum += indeg[i];
    sm[tid] = sum;
    __syncthreads();
    int val = sum;
    for (int off = 1; off < 1024; off <<= 1) {
        int t = (tid >= off) ? sm[tid - off] : 0;
        __syncthreads();
        val += t;
        sm[tid] = val;
        __syncthreads();
    }
    int prefix = val - sum;   // exclusive prefix of this thread's chunk
    for (int i = s; i < e; ++i) { offs[i] = prefix; prefix += indeg[i]; }
    if (tid == 1023) offs[N] = prefix;   // == E
}

__global__ void dinv_kernel(const int* __restrict__ indeg, float* __restrict__ dinv,
                            int N) {
    int i = blockIdx.x * blockDim.x + threadIdx.x;
    if (i < N) dinv[i] = rsqrtf((float)(indeg[i] + 1));   // +1 self loop
}

__global__ void fill_adj_kernel(const int* __restrict__ row, const int* __restrict__ col,
                                const int* __restrict__ offs, int* __restrict__ cursor,
                                int* __restrict__ adj, int E) {
    int e = blockIdx.x * blockDim.x + threadIdx.x;
    if (e < E) {
        int c = col[e];
        int pos = atomicAdd(&cursor[c], 1);
        adj[offs[c] + pos] = row[e];
    }
}

// xs[i,:] = dinv[i] * x[i,:]   (F=128, float4 over N*32)
__global__ void rowscale_kernel(const float* __restrict__ x, const float* __restrict__ dinv,
                                float* __restrict__ xs, int N) {
    int idx = blockIdx.x * blockDim.x + threadIdx.x;
    if (idx < N * 32) {
        int r = idx >> 5;
        float4 v = ((const float4*)x)[idx];
        float d = dinv[r];
        v.x *= d; v.y *= d; v.z *= d; v.w *= d;
        ((float4*)xs)[idx] = v;
    }
}

// out[i,:] = act( dinv[i] * ( sum_{e->i} hs[src] + hs[i] ) + bias )
// one wave (64 lanes) per node, float2 per lane (F=128)
__global__ void aggregate128_kernel(const float* __restrict__ hs,
                                    const int* __restrict__ offs,
                                    const int* __restrict__ adj,
                                    const float* __restrict__ dinv,
                                    const float* __restrict__ bias,
                                    float* __restrict__ out, int N, int doRelu) {
    int wid = (blockIdx.x * blockDim.x + threadIdx.x) >> 6;
    int lane = threadIdx.x & 63;
    if (wid >= N) return;
    const float2* base = (const float2*)hs;
    float2 a = base[(size_t)wid * 64 + lane];   // self term
    float ax = a.x, ay = a.y;
    int s = offs[wid], e = offs[wid + 1];
    for (int j = s; j < e; ++j) {
        int src = adj[j];
        float2 v = base[(size_t)src * 64 + lane];
        ax += v.x; ay += v.y;
    }
    float d = dinv[wid];
    ax *= d; ay *= d;
    if (bias) { ax += bias[lane * 2]; ay += bias[lane * 2 + 1]; }
    if (doRelu) { ax = fmaxf(ax, 0.f); ay = fmaxf(ay, 0.f); }
    ((float2*)out)[(size_t)wid * 64 + lane] = make_float2(ax, ay);
}

// ---------------------------------------------------------------------------
// Generic f32 GEMM: C[M,N] = epilogue( A[M,K] @ B[K,N] )
// epilogue (non-splitk): v = acc*rowscale[r]; v += bias[c]; relu
// splitk: atomicAdd into pre-zeroed C, epilogue applied by separate kernel.
// ---------------------------------------------------------------------------
template<int BM, int BN, int BK, int TM, int TN>
__global__ __launch_bounds__(256)
void gemm_f32_kernel(const float* __restrict__ A, const float* __restrict__ B,
                     float* __restrict__ C, const float* __restrict__ rowscale,
                     const float* __restrict__ bias, int M, int N, int K,
                     int kChunk, int doRelu, int splitk) {
    constexpr int TX = BN / TN;
    constexpr int TY = BM / TM;
    static_assert(TX * TY == 256, "block must be 256 threads");
    __shared__ float As[BK][BM + 4];   // transposed A tile: As[k][m]
    __shared__ float Bs[BK][BN];

    int tid = threadIdx.x;
    int tx = tid % TX, ty = tid / TX;
    int bm = blockIdx.x * BM, bn = blockIdx.y * BN;
    int k0 = blockIdx.z * kChunk;
    int k1 = k0 + kChunk; if (k1 > K) k1 = K;

    float acc[TM][TN];
#pragma unroll
    for (int i = 0; i < TM; ++i)
#pragma unroll
        for (int j = 0; j < TN; ++j) acc[i][j] = 0.f;

    for (int kk = k0; kk < k1; kk += BK) {
        constexpr int AV = BM * BK / (256 * 4);
#pragma unroll
        for (int v = 0; v < AV; ++v) {
            int f = tid + v * 256;
            int r = f / (BK / 4), c4 = f % (BK / 4);
            int grow = bm + r;
            float4 val = make_float4(0.f, 0.f, 0.f, 0.f);
            if (grow < M)
                val = *(const float4*)(A + (size_t)grow * K + kk + c4 * 4);
            As[c4 * 4 + 0][r] = val.x;
            As[c4 * 4 + 1][r] = val.y;
            As[c4 * 4 + 2][r] = val.z;
            As[c4 * 4 + 3][r] = val.w;
        }
        constexpr int BV = BN * BK / (256 * 4);
#pragma unroll
        for (int v = 0; v < BV; ++v) {
            int f = tid + v * 256;
            int r = f / (BN / 4), c4 = f % (BN / 4);
            *(float4*)(&Bs[r][c4 * 4]) =
                *(const float4*)(B + (size_t)(kk + r) * N + bn + c4 * 4);
        }
        __syncthreads();
#pragma unroll
        for (int k = 0; k < BK; ++k) {
            float a[TM], b[TN];
#pragma unroll
            for (int i = 0; i < TM; i += 4)
                *(float4*)&a[i] = *(const float4*)&As[k][ty * TM + i];
#pragma unroll
            for (int j = 0; j < TN; j += 4)
                *(float4*)&b[j] = *(const float4*)&Bs[k][tx * TN + j];
#pragma unroll
            for (int i = 0; i < TM; ++i)
#pragma unroll
                for (int j = 0; j < TN; ++j) acc[i][j] += a[i] * b[j];
        }
        __syncthreads();
    }

#pragma unroll
    for (int i = 0; i < TM; ++i) {
        int r = bm + ty * TM + i;
        if (r >= M) continue;
        float rs = rowscale ? rowscale[r] : 1.f;
#pragma unroll
        for (int j = 0; j < TN; ++j) {
            int c = bn + tx * TN + j;
            float v = acc[i][j];
            if (splitk) {
                atomicAdd(&C[(size_t)r * N + c], v);
            } else {
                v *= rs;
                if (bias) v += bias[c];
                if (doRelu) v = fmaxf(v, 0.f);
                C[(size_t)r * N + c] = v;
            }
        }
    }
}

// out = (relu?)(acc + bias[col])
__global__ void bias_act_kernel(const float* __restrict__ acc, const float* __restrict__ bias,
                                float* __restrict__ out, int total, int Ncols, int doRelu) {
    int idx = blockIdx.x * blockDim.x + threadIdx.x;
    if (idx < total) {
        int c = idx % Ncols;
        float v = acc[idx] + bias[c];
        if (doRelu) v = fmaxf(v, 0.f);
        out[idx] = v;
    }
}

// one block per graph: binary search node range in sorted batch vector, mean rows
__global__ void pool_kernel(const float* __restrict__ feats, const int* __restrict__ batch,
                            float* __restrict__ g, int N) {
    int gid = blockIdx.x;
    int lo = 0, hi = N;
    while (lo < hi) { int m = (lo + hi) >> 1; if (batch[m] < gid) lo = m + 1; else hi = m; }
    int start = lo;
    lo = start; hi = N;
    while (lo < hi) { int m = (lo + hi) >> 1; if (batch[m] < gid + 1) lo = m + 1; else hi = m; }
    int end = lo;
    int tid = threadIdx.x;    // 128 threads, one feature each
    float acc = 0.f;
    for (int i = start; i < end; ++i) acc += feats[(size_t)i * 128 + tid];
    int cnt = end - start; if (cnt < 1) cnt = 1;
    g[gid * 128 + tid] = acc / (float)cnt;
}

// ---------------------------------------------------------------------------

extern "C" void kernel_launch(void* const* d_in, const int* in_sizes, int n_in,
                              void* d_out, int out_size, void* d_ws, size_t ws_size,
                              hipStream_t stream) {
    const float* x    = (const float*)d_in[0];
    const int*   ei   = (const int*)d_in[1];
    const int*   batch= (const int*)d_in[2];
    const float* W1   = (const float*)d_in[3];
    const float* b1   = (const float*)d_in[4];
    const float* W2   = (const float*)d_in[5];
    const float* b2   = (const float*)d_in[6];
    const float* Wl1  = (const float*)d_in[7];
    const float* bl1  = (const float*)d_in[8];
    const float* Wl2  = (const float*)d_in[9];
    const float* bl2  = (const float*)d_in[10];
    const float* Wl22 = (const float*)d_in[11];
    const float* bl22 = (const float*)d_in[12];
    const float* Wl23 = (const float*)d_in[13];
    const float* bl23 = (const float*)d_in[14];
    const float* Wl3  = (const float*)d_in[15];
    const float* bl3  = (const float*)d_in[16];

    const int D = 128;
    const int N = in_sizes[0] / D;          // 50000
    const int E = in_sizes[1] / 2;          // 800000
    const int G = out_size / D;             // 256
    const int H = in_sizes[10];             // 1024
    const int* row = ei;
    const int* col = ei + E;
    float* out = (float*)d_out;

    // workspace carve-out (~110 MB)
    char* ws = (char*)d_ws;
    auto alloc = [&](size_t bytes) -> void* {
        void* p = (void*)ws;
        ws += (bytes + 255) & ~(size_t)255;
        return p;
    };
    int*   indeg  = (int*)alloc((size_t)N * 4);
    int*   cursor = (int*)alloc((size_t)N * 4);
    int*   offs   = (int*)alloc((size_t)(N + 1) * 4);
    int*   adj    = (int*)alloc((size_t)E * 4);
    float* dinv   = (float*)alloc((size_t)N * 4);
    float* xs     = (float*)alloc((size_t)N * 128 * 4);   // later reused as hs2
    float* y      = (float*)alloc((size_t)N * 128 * 4);   // later reused as out2
    float* out1   = (float*)alloc((size_t)N * 256 * 4);
    float* g      = (float*)alloc((size_t)G * 128 * 4);
    float* m1     = (float*)alloc((size_t)G * 128 * 4);   // L1 out, later splitk acc for L3
    float* g2     = (float*)alloc((size_t)G * H * 4);
    float* g3     = (float*)alloc((size_t)G * H * 4);
    float* accb   = (float*)alloc((size_t)G * H * 4);

    // ---- CSR build + normalization ----
    hipMemsetAsync(indeg, 0, (size_t)N * 4, stream);
    hipMemsetAsync(cursor, 0, (size_t)N * 4, stream);
    count_deg_kernel<<<(E + 255) / 256, 256, 0, stream>>>(col, E, indeg);
    scan_kernel<<<1, 1024, 0, stream>>>(indeg, offs, N);
    dinv_kernel<<<(N + 255) / 256, 256, 0, stream>>>(indeg, dinv, N);
    fill_adj_kernel<<<(E + 255) / 256, 256, 0, stream>>>(row, col, offs, cursor, adj, E);

    // ---- Layer 1: y = Ahat @ x  (aggregate first: 128-wide), then GEMM ----
    rowscale_kernel<<<(N * 32 + 255) / 256, 256, 0, stream>>>(x, dinv, xs, N);
    aggregate128_kernel<<<(N + 3) / 4, 256, 0, stream>>>(xs, offs, adj, dinv, nullptr, y, N, 0);
    {   // out1 = relu(y @ W1 + b1)   [N,256]
        dim3 grid((N + 127) / 128, 256 / 128, 1);
        gemm_f32_kernel<128, 128, 32, 8, 8><<<grid, 256, 0, stream>>>(
            y, W1, out1, nullptr, b1, N, 256, 128, 128, 1, 0);
    }

    // ---- Layer 2: hs2 = dinv * (out1 @ W2), then aggregate + b2 + relu ----
    {   // xs reused as hs2 [N,128]
        dim3 grid((N + 127) / 128, 1, 1);
        gemm_f32_kernel<128, 128, 32, 8, 8><<<grid, 256, 0, stream>>>(
            out1, W2, xs, dinv, nullptr, N, 128, 256, 256, 0, 0);
    }
    aggregate128_kernel<<<(N + 3) / 4, 256, 0, stream>>>(xs, offs, adj, dinv, b2, y, N, 1);

    // ---- global mean pool ----
    pool_kernel<<<G, 128, 0, stream>>>(y, batch, g, N);

    // ---- MLP ----
    {   // m1 = relu(g @ Wl1 + bl1)        [G,128], K=128
        dim3 grid((G + 63) / 64, 128 / 64, 1);
        gemm_f32_kernel<64, 64, 32, 4, 4><<<grid, 256, 0, stream>>>(
            g, Wl1, m1, nullptr, bl1, G, 128, 128, 128, 1, 0);
    }
    {   // g2 = relu(m1 @ Wl2 + bl2)       [G,1024], K=128
        dim3 grid((G + 63) / 64, H / 64, 1);
        gemm_f32_kernel<64, 64, 32, 4, 4><<<grid, 256, 0, stream>>>(
            m1, Wl2, g2, nullptr, bl2, G, H, 128, 128, 1, 0);
    }
    {   // g3 = relu(g2 @ Wl22 + bl22)     [G,1024], K=1024 split-K x4
        hipMemsetAsync(accb, 0, (size_t)G * H * 4, stream);
        dim3 grid((G + 63) / 64, H / 64, 4);
        gemm_f32_kernel<64, 64, 32, 4, 4><<<grid, 256, 0, stream>>>(
            g2, Wl22, accb, nullptr, nullptr, G, H, H, 256, 0, 1);
        bias_act_kernel<<<(G * H + 255) / 256, 256, 0, stream>>>(accb, bl22, g3, G * H, H, 1);
    }
    {   // g2 = relu(g3 @ Wl23 + bl23)     [G,1024], K=1024 split-K x4
        hipMemsetAsync(accb, 0, (size_t)G * H * 4, stream);
        dim3 grid((G + 63) / 64, H / 64, 4);
        gemm_f32_kernel<64, 64, 32, 4, 4><<<grid, 256, 0, stream>>>(
            g3, Wl23, accb, nullptr, nullptr, G, H, H, 256, 0, 1);
        bias_act_kernel<<<(G * H + 255) / 256, 256, 0, stream>>>(accb, bl23, g2, G * H, H, 1);
    }
    {   // out = g2 @ Wl3 + bl3            [G,128], K=1024 split-K x8 (no relu)
        hipMemsetAsync(m1, 0, (size_t)G * 128 * 4, stream);
        dim3 grid((G + 63) / 64, 128 / 64, 8);
        gemm_f32_kernel<64, 64, 32, 4, 4><<<grid, 256, 0, stream>>>(
            g2, Wl3, m1, nullptr, nullptr, G, 128, H, 128, 0, 1);
        bias_act_kernel<<<(G * 128 + 255) / 256, 256, 0, stream>>>(m1, bl3, out, G * 128, 128, 0);
    }
}

// Round 2
// 574.169 us; speedup vs baseline: 1.1991x; 1.1991x over previous
//
#include <hip/hip_runtime.h>

// ---------------------------------------------------------------------------
// PatternEncoder: 2x GCNConv -> global_mean_pool -> 5-layer MLP
// N=50000, E=800000, D=128, G=256, H=1024
//
// Node GEMMs now use MFMA bf16x3 (split-float: C = Ah@Bh + Ah@Bl + Al@Bh),
// rel err ~2^-17. Aggregation is pull-based CSR, dinv folded in.
// ---------------------------------------------------------------------------

typedef __attribute__((ext_vector_type(8))) short bf16x8;
typedef __attribute__((ext_vector_type(4))) float f32x4;

__device__ __forceinline__ ushort f2bf(float f) {
    unsigned u = __float_as_uint(f);
    unsigned r = (u + 0x7FFFu + ((u >> 16) & 1u)) >> 16;
    return (ushort)r;
}
__device__ __forceinline__ float bf2f(ushort h) {
    return __uint_as_float(((unsigned)h) << 16);
}

// ------------------------------ CSR build ---------------------------------

__global__ void count_deg_kernel(const int* __restrict__ col, int E,
                                 int* __restrict__ indeg) {
    int i = blockIdx.x * blockDim.x + threadIdx.x;
    if (i < E) atomicAdd(&indeg[col[i]], 1);
}

__global__ void scan_kernel(const int* __restrict__ indeg, int* __restrict__ offs,
                            int N) {
    __shared__ int sm[1024];
    int tid = threadIdx.x;
    int chunk = (N + 1023) / 1024;
    int s = tid * chunk;
    int e = s + chunk; if (e > N) e = N; if (s > N) s = N;
    int sum = 0;
    for (int i = s; i < e; ++i) sum += indeg[i];
    sm[tid] = sum;
    __syncthreads();
    int val = sum;
    for (int off = 1; off < 1024; off <<= 1) {
        int t = (tid >= off) ? sm[tid - off] : 0;
        __syncthreads();
        val += t;
        sm[tid] = val;
        __syncthreads();
    }
    int prefix = val - sum;
    for (int i = s; i < e; ++i) { offs[i] = prefix; prefix += indeg[i]; }
    if (tid == 1023) offs[N] = prefix;
}

__global__ void dinv_kernel(const int* __restrict__ indeg, float* __restrict__ dinv,
                            int N) {
    int i = blockIdx.x * blockDim.x + threadIdx.x;
    if (i < N) dinv[i] = rsqrtf((float)(indeg[i] + 1));
}

__global__ void fill_adj_kernel(const int* __restrict__ row, const int* __restrict__ col,
                                const int* __restrict__ offs, int* __restrict__ cursor,
                                int* __restrict__ adj, int E) {
    int e = blockIdx.x * blockDim.x + threadIdx.x;
    if (e < E) {
        int c = col[e];
        int pos = atomicAdd(&cursor[c], 1);
        adj[offs[c] + pos] = row[e];
    }
}

// ------------------------- weight transpose+split --------------------------
// W [K][Nn] f32 -> Th,Tl [Nn][K] bf16
__global__ void transpose_split_kernel(const float* __restrict__ W,
                                       ushort* __restrict__ Th, ushort* __restrict__ Tl,
                                       int K, int Nn) {
    int idx = blockIdx.x * blockDim.x + threadIdx.x;
    if (idx < K * Nn) {
        int k = idx / Nn, n = idx % Nn;
        float v = W[idx];
        ushort h = f2bf(v);
        Th[(size_t)n * K + k] = h;
        Tl[(size_t)n * K + k] = f2bf(v - bf2f(h));
    }
}

// ------------------------------ aggregation --------------------------------
// MODE 1 (layer 1): out = dinv[i]*(sum dinv[src]*x[src] + dinv[i]*x[i]); write bf16 hi/lo
// MODE 0 (layer 2): out = relu(dinv[i]*(sum hs[src] + hs[i]) + bias);     write f32
template<int MODE>
__global__ void aggregate128_kernel(const float* __restrict__ hs,
                                    const int* __restrict__ offs,
                                    const int* __restrict__ adj,
                                    const float* __restrict__ dinv,
                                    const float* __restrict__ bias,
                                    float* __restrict__ outf,
                                    ushort* __restrict__ outh, ushort* __restrict__ outl,
                                    int N) {
    int wid = (blockIdx.x * blockDim.x + threadIdx.x) >> 6;
    int lane = threadIdx.x & 63;
    if (wid >= N) return;
    const float2* base = (const float2*)hs;
    float dself = dinv[wid];
    float2 a = base[(size_t)wid * 64 + lane];
    float ax, ay;
    if (MODE == 1) { ax = a.x * dself; ay = a.y * dself; }
    else           { ax = a.x;         ay = a.y; }
    int s = offs[wid], e = offs[wid + 1];
    for (int j = s; j < e; ++j) {
        int src = adj[j];
        float2 v = base[(size_t)src * 64 + lane];
        if (MODE == 1) { float d = dinv[src]; ax += v.x * d; ay += v.y * d; }
        else           { ax += v.x; ay += v.y; }
    }
    ax *= dself; ay *= dself;
    if (MODE == 0) {
        float2 b = ((const float2*)bias)[lane];
        ax = fmaxf(ax + b.x, 0.f); ay = fmaxf(ay + b.y, 0.f);
        ((float2*)outf)[(size_t)wid * 64 + lane] = make_float2(ax, ay);
    } else {
        ushort h0 = f2bf(ax), h1 = f2bf(ay);
        ushort l0 = f2bf(ax - bf2f(h0)), l1 = f2bf(ay - bf2f(h1));
        ((ushort2*)outh)[(size_t)wid * 64 + lane] = make_ushort2(h0, h1);
        ((ushort2*)outl)[(size_t)wid * 64 + lane] = make_ushort2(l0, l1);
    }
}

// --------------------------- MFMA bf16x3 GEMM ------------------------------
// C[M,N] = A[M,K] @ B[K,N], A given as (Ah,Al) bf16 row-major [M,K] (rows
// padded so staging can read full 128-row tiles), B given transposed+split
// (Bth,Btl) bf16 [N][K]. Tile 128x128, BK=32, 4 waves (2x2), 64x64 per wave.
// EPI 1: v += bias[col]; relu; write bf16 hi/lo (for next GEMM's A)
// EPI 0: v *= rowscale[row]; write f32
#define SWZ(r) (((r) >> 1) & 3)

template<int EPI>
__global__ __launch_bounds__(256) void gemm_bf16x3_kernel(
        const ushort* __restrict__ Ah, const ushort* __restrict__ Al,
        const ushort* __restrict__ Bth, const ushort* __restrict__ Btl,
        const float* __restrict__ bias, const float* __restrict__ rowscale,
        float* __restrict__ Cf, ushort* __restrict__ Ch, ushort* __restrict__ Cl,
        int M, int N, int K) {
    __shared__ __align__(16) ushort lds[4][128][32];   // Ah, Al, Bh, Bl tiles

    const int tid = threadIdx.x;
    const int w = tid >> 6, lane = tid & 63;
    const int wr = w >> 1, wc = w & 1;
    const int bm = blockIdx.x * 128, bn = blockIdx.y * 128;

    const ushort* srcs[4] = {
        Ah  + (size_t)bm * K, Al  + (size_t)bm * K,
        Bth + (size_t)bn * K, Btl + (size_t)bn * K };

    f32x4 acc[4][4];
#pragma unroll
    for (int i = 0; i < 4; ++i)
#pragma unroll
        for (int j = 0; j < 4; ++j) acc[i][j] = (f32x4)0.f;

    const int s = lane >> 4, r16 = lane & 15;

    for (int k0 = 0; k0 < K; k0 += 32) {
        // ---- stage 4 tiles (8KB each) via global_load_lds, swizzled source
#pragma unroll
        for (int t = 0; t < 4; ++t) {
#pragma unroll
            for (int v = 0; v < 2; ++v) {
                int chunk = v * 4 + w;                 // 0..7 -> 16 rows each
                int row = chunk * 16 + (lane >> 2);
                int u = lane & 3;                      // 16B slot within row
                int col = k0 + 8 * (u ^ SWZ(row));     // pre-swizzled source
                const ushort* g = srcs[t] + (size_t)row * K + col;
                ushort* l = &lds[t][chunk * 16][0];    // wave-uniform base
                __builtin_amdgcn_global_load_lds(
                    (const __attribute__((address_space(1))) void*)g,
                    (__attribute__((address_space(3))) void*)l, 16, 0, 0);
            }
        }
        __syncthreads();

        // ---- fragments (swizzled ds_read_b128)
        bf16x8 ah[4], al[4], bh[4], bl[4];
#pragma unroll
        for (int f = 0; f < 4; ++f) {
            int ra = wr * 64 + f * 16 + r16;
            int oa = ra * 64 + 16 * (s ^ SWZ(ra));
            ah[f] = *(const bf16x8*)((const char*)&lds[0][0][0] + oa);
            al[f] = *(const bf16x8*)((const char*)&lds[1][0][0] + oa);
            int rb = wc * 64 + f * 16 + r16;
            int ob = rb * 64 + 16 * (s ^ SWZ(rb));
            bh[f] = *(const bf16x8*)((const char*)&lds[2][0][0] + ob);
            bl[f] = *(const bf16x8*)((const char*)&lds[3][0][0] + ob);
        }

        // ---- 3-term MFMA accumulate
#pragma unroll
        for (int i = 0; i < 4; ++i)
#pragma unroll
            for (int j = 0; j < 4; ++j) {
                acc[i][j] = __builtin_amdgcn_mfma_f32_16x16x32_bf16(ah[i], bh[j], acc[i][j], 0, 0, 0);
                acc[i][j] = __builtin_amdgcn_mfma_f32_16x16x32_bf16(ah[i], bl[j], acc[i][j], 0, 0, 0);
                acc[i][j] = __builtin_amdgcn_mfma_f32_16x16x32_bf16(al[i], bh[j], acc[i][j], 0, 0, 0);
            }
        __syncthreads();
    }

    // ---- epilogue: C/D layout col=lane&15, row=(lane>>4)*4+reg (m89-verified)
    const int q4 = lane >> 4;
#pragma unroll
    for (int i = 0; i < 4; ++i) {
        int row0 = bm + wr * 64 + i * 16 + q4 * 4;
        if (row0 >= M) continue;                 // M%16==0 -> whole band valid
#pragma unroll
        for (int j = 0; j < 4; ++j) {
            int colc = bn + wc * 64 + j * 16 + r16;
            if (EPI == 1) {
                float bv = bias[colc];
#pragma unroll
                for (int r = 0; r < 4; ++r) {
                    float v = fmaxf(acc[i][j][r] + bv, 0.f);
                    ushort h = f2bf(v);
                    ushort lo = f2bf(v - bf2f(h));
                    size_t o = (size_t)(row0 + r) * N + colc;
                    Ch[o] = h; Cl[o] = lo;
                }
            } else {
#pragma unroll
                for (int r = 0; r < 4; ++r) {
                    float v = acc[i][j][r] * rowscale[row0 + r];
                    Cf[(size_t)(row0 + r) * N + colc] = v;
                }
            }
        }
    }
}

// ---------------------------- f32 GEMM (MLP) --------------------------------
template<int BM, int BN, int BK, int TM, int TN>
__global__ __launch_bounds__(256)
void gemm_f32_kernel(const float* __restrict__ A, const float* __restrict__ B,
                     float* __restrict__ C, const float* __restrict__ rowscale,
                     const float* __restrict__ bias, int M, int N, int K,
                     int kChunk, int doRelu, int splitk) {
    constexpr int TX = BN / TN;
    constexpr int TY = BM / TM;
    static_assert(TX * TY == 256, "block must be 256 threads");
    __shared__ float As[BK][BM + 4];
    __shared__ float Bs[BK][BN];

    int tid = threadIdx.x;
    int tx = tid % TX, ty = tid / TX;
    int bm = blockIdx.x * BM, bn = blockIdx.y * BN;
    int k0 = blockIdx.z * kChunk;
    int k1 = k0 + kChunk; if (k1 > K) k1 = K;

    float acc[TM][TN];
#pragma unroll
    for (int i = 0; i < TM; ++i)
#pragma unroll
        for (int j = 0; j < TN; ++j) acc[i][j] = 0.f;

    for (int kk = k0; kk < k1; kk += BK) {
        constexpr int AV = BM * BK / (256 * 4);
#pragma unroll
        for (int v = 0; v < AV; ++v) {
            int f = tid + v * 256;
            int r = f / (BK / 4), c4 = f % (BK / 4);
            int grow = bm + r;
            float4 val = make_float4(0.f, 0.f, 0.f, 0.f);
            if (grow < M)
                val = *(const float4*)(A + (size_t)grow * K + kk + c4 * 4);
            As[c4 * 4 + 0][r] = val.x;
            As[c4 * 4 + 1][r] = val.y;
            As[c4 * 4 + 2][r] = val.z;
            As[c4 * 4 + 3][r] = val.w;
        }
        constexpr int BV = BN * BK / (256 * 4);
#pragma unroll
        for (int v = 0; v < BV; ++v) {
            int f = tid + v * 256;
            int r = f / (BN / 4), c4 = f % (BN / 4);
            *(float4*)(&Bs[r][c4 * 4]) =
                *(const float4*)(B + (size_t)(kk + r) * N + bn + c4 * 4);
        }
        __syncthreads();
#pragma unroll
        for (int k = 0; k < BK; ++k) {
            float a[TM], b[TN];
#pragma unroll
            for (int i = 0; i < TM; i += 4)
                *(float4*)&a[i] = *(const float4*)&As[k][ty * TM + i];
#pragma unroll
            for (int j = 0; j < TN; j += 4)
                *(float4*)&b[j] = *(const float4*)&Bs[k][tx * TN + j];
#pragma unroll
            for (int i = 0; i < TM; ++i)
#pragma unroll
                for (int j = 0; j < TN; ++j) acc[i][j] += a[i] * b[j];
        }
        __syncthreads();
    }

#pragma unroll
    for (int i = 0; i < TM; ++i) {
        int r = bm + ty * TM + i;
        if (r >= M) continue;
        float rs = rowscale ? rowscale[r] : 1.f;
#pragma unroll
        for (int j = 0; j < TN; ++j) {
            int c = bn + tx * TN + j;
            float v = acc[i][j];
            if (splitk) {
                atomicAdd(&C[(size_t)r * N + c], v);
            } else {
                v *= rs;
                if (bias) v += bias[c];
                if (doRelu) v = fmaxf(v, 0.f);
                C[(size_t)r * N + c] = v;
            }
        }
    }
}

__global__ void bias_act_kernel(const float* __restrict__ acc, const float* __restrict__ bias,
                                float* __restrict__ out, int total, int Ncols, int doRelu) {
    int idx = blockIdx.x * blockDim.x + threadIdx.x;
    if (idx < total) {
        int c = idx % Ncols;
        float v = acc[idx] + bias[c];
        if (doRelu) v = fmaxf(v, 0.f);
        out[idx] = v;
    }
}

__global__ void pool_kernel(const float* __restrict__ feats, const int* __restrict__ batch,
                            float* __restrict__ g, int N) {
    int gid = blockIdx.x;
    int lo = 0, hi = N;
    while (lo < hi) { int m = (lo + hi) >> 1; if (batch[m] < gid) lo = m + 1; else hi = m; }
    int start = lo;
    lo = start; hi = N;
    while (lo < hi) { int m = (lo + hi) >> 1; if (batch[m] < gid + 1) lo = m + 1; else hi = m; }
    int end = lo;
    int tid = threadIdx.x;
    float acc = 0.f;
    for (int i = start; i < end; ++i) acc += feats[(size_t)i * 128 + tid];
    int cnt = end - start; if (cnt < 1) cnt = 1;
    g[gid * 128 + tid] = acc / (float)cnt;
}

// ---------------------------------------------------------------------------

extern "C" void kernel_launch(void* const* d_in, const int* in_sizes, int n_in,
                              void* d_out, int out_size, void* d_ws, size_t ws_size,
                              hipStream_t stream) {
    const float* x    = (const float*)d_in[0];
    const int*   ei   = (const int*)d_in[1];
    const int*   batch= (const int*)d_in[2];
    const float* W1   = (const float*)d_in[3];
    const float* b1   = (const float*)d_in[4];
    const float* W2   = (const float*)d_in[5];
    const float* b2   = (const float*)d_in[6];
    const float* Wl1  = (const float*)d_in[7];
    const float* bl1  = (const float*)d_in[8];
    const float* Wl2  = (const float*)d_in[9];
    const float* bl2  = (const float*)d_in[10];
    const float* Wl22 = (const float*)d_in[11];
    const float* bl22 = (const float*)d_in[12];
    const float* Wl23 = (const float*)d_in[13];
    const float* bl23 = (const float*)d_in[14];
    const float* Wl3  = (const float*)d_in[15];
    const float* bl3  = (const float*)d_in[16];

    const int D = 128;
    const int N = in_sizes[0] / D;           // 50000
    const int E = in_sizes[1] / 2;           // 800000
    const int G = out_size / D;              // 256
    const int H = in_sizes[10];              // 1024
    const int Mpad = ((N + 127) / 128) * 128; // 50048
    const int* row = ei;
    const int* col = ei + E;
    float* out = (float*)d_out;

    char* ws = (char*)d_ws;
    auto alloc = [&](size_t bytes) -> void* {
        void* p = (void*)ws;
        ws += (bytes + 255) & ~(size_t)255;
        return p;
    };
    int*    indeg  = (int*)alloc((size_t)N * 4);
    int*    cursor = (int*)alloc((size_t)N * 4);
    int*    offs   = (int*)alloc((size_t)(N + 1) * 4);
    int*    adj    = (int*)alloc((size_t)E * 4);
    float*  dinv   = (float*)alloc((size_t)N * 4);
    ushort* W1th   = (ushort*)alloc((size_t)256 * 128 * 2);
    ushort* W1tl   = (ushort*)alloc((size_t)256 * 128 * 2);
    ushort* W2th   = (ushort*)alloc((size_t)128 * 256 * 2);
    ushort* W2tl   = (ushort*)alloc((size_t)128 * 256 * 2);
    ushort* yh     = (ushort*)alloc((size_t)Mpad * 128 * 2);   // 12.8 MB
    ushort* yl     = (ushort*)alloc((size_t)Mpad * 128 * 2);   // 12.8 MB
    ushort* out1h  = (ushort*)alloc((size_t)Mpad * 256 * 2);   // 25.6 MB
    ushort* out1l  = (ushort*)alloc((size_t)Mpad * 256 * 2);   // 25.6 MB
    float*  g      = (float*)alloc((size_t)G * 128 * 4);
    float*  m1     = (float*)alloc((size_t)G * 128 * 4);
    float*  g2     = (float*)alloc((size_t)G * H * 4);
    float*  g3     = (float*)alloc((size_t)G * H * 4);
    float*  accb   = (float*)alloc((size_t)G * H * 4);

    // aliases (lifetimes disjoint):
    float* hs2 = (float*)yh;     // [N,128] f32, written by gemm2 after yh/yl dead
    float* y   = (float*)out1h;  // [N,128] f32, written by aggregate2 after out1 dead

    // ---- CSR build + normalization ----
    hipMemsetAsync(indeg, 0, (size_t)N * 4, stream);
    hipMemsetAsync(cursor, 0, (size_t)N * 4, stream);
    count_deg_kernel<<<(E + 255) / 256, 256, 0, stream>>>(col, E, indeg);
    scan_kernel<<<1, 1024, 0, stream>>>(indeg, offs, N);
    dinv_kernel<<<(N + 255) / 256, 256, 0, stream>>>(indeg, dinv, N);
    fill_adj_kernel<<<(E + 255) / 256, 256, 0, stream>>>(row, col, offs, cursor, adj, E);

    // ---- weight transpose + split ----
    transpose_split_kernel<<<(128 * 256 + 255) / 256, 256, 0, stream>>>(W1, W1th, W1tl, 128, 256);
    transpose_split_kernel<<<(256 * 128 + 255) / 256, 256, 0, stream>>>(W2, W2th, W2tl, 256, 128);

    // ---- Layer 1: aggregate (dinv folded) -> bf16 split ----
    aggregate128_kernel<1><<<(N + 3) / 4, 256, 0, stream>>>(
        x, offs, adj, dinv, nullptr, nullptr, yh, yl, N);
    {   // out1(h,l) = split(relu(y @ W1 + b1))   [N,256]
        dim3 grid(Mpad / 128, 256 / 128);
        gemm_bf16x3_kernel<1><<<grid, 256, 0, stream>>>(
            yh, yl, W1th, W1tl, b1, nullptr, nullptr, out1h, out1l, N, 256, 128);
    }

    // ---- Layer 2: hs2 = dinv * (out1 @ W2); aggregate + b2 + relu ----
    {
        dim3 grid(Mpad / 128, 128 / 128);
        gemm_bf16x3_kernel<0><<<grid, 256, 0, stream>>>(
            out1h, out1l, W2th, W2tl, nullptr, dinv, hs2, nullptr, nullptr, N, 128, 256);
    }
    aggregate128_kernel<0><<<(N + 3) / 4, 256, 0, stream>>>(
        hs2, offs, adj, dinv, b2, y, nullptr, nullptr, N);

    // ---- global mean pool ----
    pool_kernel<<<G, 128, 0, stream>>>(y, batch, g, N);

    // ---- MLP (f32 path) ----
    {   // m1 = relu(g @ Wl1 + bl1)        [G,128]
        dim3 grid((G + 63) / 64, 128 / 64);
        gemm_f32_kernel<64, 64, 32, 4, 4><<<grid, 256, 0, stream>>>(
            g, Wl1, m1, nullptr, bl1, G, 128, 128, 128, 1, 0);
    }
    {   // g2 = relu(m1 @ Wl2 + bl2)       [G,1024]
        dim3 grid((G + 63) / 64, H / 64);
        gemm_f32_kernel<64, 64, 32, 4, 4><<<grid, 256, 0, stream>>>(
            m1, Wl2, g2, nullptr, bl2, G, H, 128, 128, 1, 0);
    }
    {   // g3 = relu(g2 @ Wl22 + bl22)     [G,1024] split-K x4
        hipMemsetAsync(accb, 0, (size_t)G * H * 4, stream);
        dim3 grid((G + 63) / 64, H / 64, 4);
        gemm_f32_kernel<64, 64, 32, 4, 4><<<grid, 256, 0, stream>>>(
            g2, Wl22, accb, nullptr, nullptr, G, H, H, 256, 0, 1);
        bias_act_kernel<<<(G * H + 255) / 256, 256, 0, stream>>>(accb, bl22, g3, G * H, H, 1);
    }
    {   // g2 = relu(g3 @ Wl23 + bl23)     [G,1024] split-K x4
        hipMemsetAsync(accb, 0, (size_t)G * H * 4, stream);
        dim3 grid((G + 63) / 64, H / 64, 4);
        gemm_f32_kernel<64, 64, 32, 4, 4><<<grid, 256, 0, stream>>>(
            g3, Wl23, accb, nullptr, nullptr, G, H, H, 256, 0, 1);
        bias_act_kernel<<<(G * H + 255) / 256, 256, 0, stream>>>(accb, bl23, g2, G * H, H, 1);
    }
    {   // out = g2 @ Wl3 + bl3            [G,128] split-K x8
        hipMemsetAsync(m1, 0, (size_t)G * 128 * 4, stream);
        dim3 grid((G + 63) / 64, 128 / 64, 8);
        gemm_f32_kernel<64, 64, 32, 4, 4><<<grid, 256, 0, stream>>>(
            g2, Wl3, m1, nullptr, nullptr, G, 128, H, 128, 0, 1);
        bias_act_kernel<<<(G * 128 + 255) / 256, 256, 0, stream>>>(m1, bl3, out, G * 128, 128, 0);
    }
}

// Round 3
// 566.362 us; speedup vs baseline: 1.2156x; 1.0138x over previous
//
#include <hip/hip_runtime.h>

// ---------------------------------------------------------------------------
// PatternEncoder: 2x GCNConv -> global_mean_pool -> 5-layer MLP
// N=50000, E=800000, D=128, G=256, H=1024
//
// Node GEMMs now use MFMA bf16x3 (split-float: C = Ah@Bh + Ah@Bl + Al@Bh),
// rel err ~2^-17. Aggregation is pull-based CSR, dinv folded in.
// ---------------------------------------------------------------------------

typedef __attribute__((ext_vector_type(8))) short bf16x8;
typedef __attribute__((ext_vector_type(4))) float f32x4;

__device__ __forceinline__ ushort f2bf(float f) {
    unsigned u = __float_as_uint(f);
    unsigned r = (u + 0x7FFFu + ((u >> 16) & 1u)) >> 16;
    return (ushort)r;
}
__device__ __forceinline__ float bf2f(ushort h) {
    return __uint_as_float(((unsigned)h) << 16);
}

// ------------------------------ CSR build ---------------------------------

__global__ void count_deg_kernel(const int* __restrict__ col, int E,
                                 int* __restrict__ indeg) {
    int i = blockIdx.x * blockDim.x + threadIdx.x;
    if (i < E) atomicAdd(&indeg[col[i]], 1);
}

__global__ void scan_kernel(const int* __restrict__ indeg, int* __restrict__ offs,
                            int N) {
    __shared__ int sm[1024];
    int tid = threadIdx.x;
    int chunk = (N + 1023) / 1024;
    int s = tid * chunk;
    int e = s + chunk; if (e > N) e = N; if (s > N) s = N;
    int sum = 0;
    for (int i = s; i < e; ++i) sum += indeg[i];
    sm[tid] = sum;
    __syncthreads();
    int val = sum;
    for (int off = 1; off < 1024; off <<= 1) {
        int t = (tid >= off) ? sm[tid - off] : 0;
        __syncthreads();
        val += t;
        sm[tid] = val;
        __syncthreads();
    }
    int prefix = val - sum;
    for (int i = s; i < e; ++i) { offs[i] = prefix; prefix += indeg[i]; }
    if (tid == 1023) offs[N] = prefix;
}

__global__ void dinv_kernel(const int* __restrict__ indeg, float* __restrict__ dinv,
                            int N) {
    int i = blockIdx.x * blockDim.x + threadIdx.x;
    if (i < N) dinv[i] = rsqrtf((float)(indeg[i] + 1));
}

__global__ void fill_adj_kernel(const int* __restrict__ row, const int* __restrict__ col,
                                const int* __restrict__ offs, int* __restrict__ cursor,
                                int* __restrict__ adj, int E) {
    int e = blockIdx.x * blockDim.x + threadIdx.x;
    if (e < E) {
        int c = col[e];
        int pos = atomicAdd(&cursor[c], 1);
        adj[offs[c] + pos] = row[e];
    }
}

// ------------------------- weight transpose+split --------------------------
// W [K][Nn] f32 -> Th,Tl [Nn][K] bf16
__global__ void transpose_split_kernel(const float* __restrict__ W,
                                       ushort* __restrict__ Th, ushort* __restrict__ Tl,
                                       int K, int Nn) {
    int idx = blockIdx.x * blockDim.x + threadIdx.x;
    if (idx < K * Nn) {
        int k = idx / Nn, n = idx % Nn;
        float v = W[idx];
        ushort h = f2bf(v);
        Th[(size_t)n * K + k] = h;
        Tl[(size_t)n * K + k] = f2bf(v - bf2f(h));
    }
}

// ------------------------------ aggregation --------------------------------
// MODE 1 (layer 1): out = dinv[i]*(sum dinv[src]*x[src] + dinv[i]*x[i]); write bf16 hi/lo
// MODE 0 (layer 2): out = relu(dinv[i]*(sum hs[src] + hs[i]) + bias);     write f32
template<int MODE>
__global__ void aggregate128_kernel(const float* __restrict__ hs,
                                    const int* __restrict__ offs,
                                    const int* __restrict__ adj,
                                    const float* __restrict__ dinv,
                                    const float* __restrict__ bias,
                                    float* __restrict__ outf,
                                    ushort* __restrict__ outh, ushort* __restrict__ outl,
                                    int N) {
    int wid = (blockIdx.x * blockDim.x + threadIdx.x) >> 6;
    int lane = threadIdx.x & 63;
    if (wid >= N) return;
    const float2* base = (const float2*)hs;
    float dself = dinv[wid];
    float2 a = base[(size_t)wid * 64 + lane];
    float ax, ay;
    if (MODE == 1) { ax = a.x * dself; ay = a.y * dself; }
    else           { ax = a.x;         ay = a.y; }
    int s = offs[wid], e = offs[wid + 1];
    for (int j = s; j < e; ++j) {
        int src = adj[j];
        float2 v = base[(size_t)src * 64 + lane];
        if (MODE == 1) { float d = dinv[src]; ax += v.x * d; ay += v.y * d; }
        else           { ax += v.x; ay += v.y; }
    }
    ax *= dself; ay *= dself;
    if (MODE == 0) {
        float2 b = ((const float2*)bias)[lane];
        ax = fmaxf(ax + b.x, 0.f); ay = fmaxf(ay + b.y, 0.f);
        ((float2*)outf)[(size_t)wid * 64 + lane] = make_float2(ax, ay);
    } else {
        ushort h0 = f2bf(ax), h1 = f2bf(ay);
        ushort l0 = f2bf(ax - bf2f(h0)), l1 = f2bf(ay - bf2f(h1));
        ((ushort2*)outh)[(size_t)wid * 64 + lane] = make_ushort2(h0, h1);
        ((ushort2*)outl)[(size_t)wid * 64 + lane] = make_ushort2(l0, l1);
    }
}

// --------------------------- MFMA bf16x3 GEMM ------------------------------
// C[M,N] = A[M,K] @ B[K,N], A given as (Ah,Al) bf16 row-major [M,K] (rows
// padded so staging can read full 128-row tiles), B given transposed+split
// (Bth,Btl) bf16 [N][K]. Tile 128x128, BK=32, 4 waves (2x2), 64x64 per wave.
// EPI 1: v += bias[col]; relu; write bf16 hi/lo (for next GEMM's A)
// EPI 0: v *= rowscale[row]; write f32
#define SWZ(r) (((r) >> 1) & 3)

template<int EPI>
__global__ __launch_bounds__(256) void gemm_bf16x3_kernel(
        const ushort* __restrict__ Ah, const ushort* __restrict__ Al,
        const ushort* __restrict__ Bth, const ushort* __restrict__ Btl,
        const float* __restrict__ bias, const float* __restrict__ rowscale,
        float* __restrict__ Cf, ushort* __restrict__ Ch, ushort* __restrict__ Cl,
        int M, int N, int K) {
    __shared__ __align__(16) ushort lds[4][128][32];   // Ah, Al, Bh, Bl tiles

    const int tid = threadIdx.x;
    const int w = tid >> 6, lane = tid & 63;
    const int wr = w >> 1, wc = w & 1;
    const int bm = blockIdx.x * 128, bn = blockIdx.y * 128;

    const ushort* srcs[4] = {
        Ah  + (size_t)bm * K, Al  + (size_t)bm * K,
        Bth + (size_t)bn * K, Btl + (size_t)bn * K };

    f32x4 acc[4][4];
#pragma unroll
    for (int i = 0; i < 4; ++i)
#pragma unroll
        for (int j = 0; j < 4; ++j) acc[i][j] = (f32x4)0.f;

    const int s = lane >> 4, r16 = lane & 15;

    for (int k0 = 0; k0 < K; k0 += 32) {
        // ---- stage 4 tiles (8KB each) via global_load_lds, swizzled source
#pragma unroll
        for (int t = 0; t < 4; ++t) {
#pragma unroll
            for (int v = 0; v < 2; ++v) {
                int chunk = v * 4 + w;                 // 0..7 -> 16 rows each
                int row = chunk * 16 + (lane >> 2);
                int u = lane & 3;                      // 16B slot within row
                int col = k0 + 8 * (u ^ SWZ(row));     // pre-swizzled source
                const ushort* g = srcs[t] + (size_t)row * K + col;
                ushort* l = &lds[t][chunk * 16][0];    // wave-uniform base
                __builtin_amdgcn_global_load_lds(
                    (const __attribute__((address_space(1))) void*)g,
                    (__attribute__((address_space(3))) void*)l, 16, 0, 0);
            }
        }
        __syncthreads();

        // ---- fragments (swizzled ds_read_b128)
        bf16x8 ah[4], al[4], bh[4], bl[4];
#pragma unroll
        for (int f = 0; f < 4; ++f) {
            int ra = wr * 64 + f * 16 + r16;
            int oa = ra * 64 + 16 * (s ^ SWZ(ra));
            ah[f] = *(const bf16x8*)((const char*)&lds[0][0][0] + oa);
            al[f] = *(const bf16x8*)((const char*)&lds[1][0][0] + oa);
            int rb = wc * 64 + f * 16 + r16;
            int ob = rb * 64 + 16 * (s ^ SWZ(rb));
            bh[f] = *(const bf16x8*)((const char*)&lds[2][0][0] + ob);
            bl[f] = *(const bf16x8*)((const char*)&lds[3][0][0] + ob);
        }

        // ---- 3-term MFMA accumulate
#pragma unroll
        for (int i = 0; i < 4; ++i)
#pragma unroll
            for (int j = 0; j < 4; ++j) {
                acc[i][j] = __builtin_amdgcn_mfma_f32_16x16x32_bf16(ah[i], bh[j], acc[i][j], 0, 0, 0);
                acc[i][j] = __builtin_amdgcn_mfma_f32_16x16x32_bf16(ah[i], bl[j], acc[i][j], 0, 0, 0);
                acc[i][j] = __builtin_amdgcn_mfma_f32_16x16x32_bf16(al[i], bh[j], acc[i][j], 0, 0, 0);
            }
        __syncthreads();
    }

    // ---- epilogue: C/D layout col=lane&15, row=(lane>>4)*4+reg (m89-verified)
    const int q4 = lane >> 4;
#pragma unroll
    for (int i = 0; i < 4; ++i) {
        int row0 = bm + wr * 64 + i * 16 + q4 * 4;
        if (row0 >= M) continue;                 // M%16==0 -> whole band valid
#pragma unroll
        for (int j = 0; j < 4; ++j) {
            int colc = bn + wc * 64 + j * 16 + r16;
            if (EPI == 1) {
                float bv = bias[colc];
#pragma unroll
                for (int r = 0; r < 4; ++r) {
                    float v = fmaxf(acc[i][j][r] + bv, 0.f);
                    ushort h = f2bf(v);
                    ushort lo = f2bf(v - bf2f(h));
                    size_t o = (size_t)(row0 + r) * N + colc;
                    Ch[o] = h; Cl[o] = lo;
                }
            } else {
#pragma unroll
                for (int r = 0; r < 4; ++r) {
                    float v = acc[i][j][r] * rowscale[row0 + r];
                    Cf[(size_t)(row0 + r) * N + colc] = v;
                }
            }
        }
    }
}

// ---------------------------- f32 GEMM (MLP) --------------------------------
template<int BM, int BN, int BK, int TM, int TN>
__global__ __launch_bounds__(256)
void gemm_f32_kernel(const float* __restrict__ A, const float* __restrict__ B,
                     float* __restrict__ C, const float* __restrict__ rowscale,
                     const float* __restrict__ bias, int M, int N, int K,
                     int kChunk, int doRelu, int splitk) {
    constexpr int TX = BN / TN;
    constexpr int TY = BM / TM;
    static_assert(TX * TY == 256, "block must be 256 threads");
    __shared__ float As[BK][BM + 4];
    __shared__ float Bs[BK][BN];

    int tid = threadIdx.x;
    int tx = tid % TX, ty = tid / TX;
    int bm = blockIdx.x * BM, bn = blockIdx.y * BN;
    int k0 = blockIdx.z * kChunk;
    int k1 = k0 + kChunk; if (k1 > K) k1 = K;

    float acc[TM][TN];
#pragma unroll
    for (int i = 0; i < TM; ++i)
#pragma unroll
        for (int j = 0; j < TN; ++j) acc[i][j] = 0.f;

    for (int kk = k0; kk < k1; kk += BK) {
        constexpr int AV = BM * BK / (256 * 4);
#pragma unroll
        for (int v = 0; v < AV; ++v) {
            int f = tid + v * 256;
            int r = f / (BK / 4), c4 = f % (BK / 4);
            int grow = bm + r;
            float4 val = make_float4(0.f, 0.f, 0.f, 0.f);
            if (grow < M)
                val = *(const float4*)(A + (size_t)grow * K + kk + c4 * 4);
            As[c4 * 4 + 0][r] = val.x;
            As[c4 * 4 + 1][r] = val.y;
            As[c4 * 4 + 2][r] = val.z;
            As[c4 * 4 + 3][r] = val.w;
        }
        constexpr int BV = BN * BK / (256 * 4);
#pragma unroll
        for (int v = 0; v < BV; ++v) {
            int f = tid + v * 256;
            int r = f / (BN / 4), c4 = f % (BN / 4);
            *(float4*)(&Bs[r][c4 * 4]) =
                *(const float4*)(B + (size_t)(kk + r) * N + bn + c4 * 4);
        }
        __syncthreads();
#pragma unroll
        for (int k = 0; k < BK; ++k) {
            float a[TM], b[TN];
#pragma unroll
            for (int i = 0; i < TM; i += 4)
                *(float4*)&a[i] = *(const float4*)&As[k][ty * TM + i];
#pragma unroll
            for (int j = 0; j < TN; j += 4)
                *(float4*)&b[j] = *(const float4*)&Bs[k][tx * TN + j];
#pragma unroll
            for (int i = 0; i < TM; ++i)
#pragma unroll
                for (int j = 0; j < TN; ++j) acc[i][j] += a[i] * b[j];
        }
        __syncthreads();
    }

#pragma unroll
    for (int i = 0; i < TM; ++i) {
        int r = bm + ty * TM + i;
        if (r >= M) continue;
        float rs = rowscale ? rowscale[r] : 1.f;
#pragma unroll
        for (int j = 0; j < TN; ++j) {
            int c = bn + tx * TN + j;
            float v = acc[i][j];
            if (splitk) {
                atomicAdd(&C[(size_t)r * N + c], v);
            } else {
                v *= rs;
                if (bias) v += bias[c];
                if (doRelu) v = fmaxf(v, 0.f);
                C[(size_t)r * N + c] = v;
            }
        }
    }
}

__global__ void bias_act_kernel(const float* __restrict__ acc, const float* __restrict__ bias,
                                float* __restrict__ out, int total, int Ncols, int doRelu) {
    int idx = blockIdx.x * blockDim.x + threadIdx.x;
    if (idx < total) {
        int c = idx % Ncols;
        float v = acc[idx] + bias[c];
        if (doRelu) v = fmaxf(v, 0.f);
        out[idx] = v;
    }
}

__global__ void pool_kernel(const float* __restrict__ feats, const int* __restrict__ batch,
                            float* __restrict__ g, int N) {
    int gid = blockIdx.x;
    int lo = 0, hi = N;
    while (lo < hi) { int m = (lo + hi) >> 1; if (batch[m] < gid) lo = m + 1; else hi = m; }
    int start = lo;
    lo = start; hi = N;
    while (lo < hi) { int m = (lo + hi) >> 1; if (batch[m] < gid + 1) lo = m + 1; else hi = m; }
    int end = lo;
    int tid = threadIdx.x;
    float acc = 0.f;
    for (int i = start; i < end; ++i) acc += feats[(size_t)i * 128 + tid];
    int cnt = end - start; if (cnt < 1) cnt = 1;
    g[gid * 128 + tid] = acc / (float)cnt;
}

// ---------------------------------------------------------------------------

extern "C" void kernel_launch(void* const* d_in, const int* in_sizes, int n_in,
                              void* d_out, int out_size, void* d_ws, size_t ws_size,
                              hipStream_t stream) {
    const float* x    = (const float*)d_in[0];
    const int*   ei   = (const int*)d_in[1];
    const int*   batch= (const int*)d_in[2];
    const float* W1   = (const float*)d_in[3];
    const float* b1   = (const float*)d_in[4];
    const float* W2   = (const float*)d_in[5];
    const float* b2   = (const float*)d_in[6];
    const float* Wl1  = (const float*)d_in[7];
    const float* bl1  = (const float*)d_in[8];
    const float* Wl2  = (const float*)d_in[9];
    const float* bl2  = (const float*)d_in[10];
    const float* Wl22 = (const float*)d_in[11];
    const float* bl22 = (const float*)d_in[12];
    const float* Wl23 = (const float*)d_in[13];
    const float* bl23 = (const float*)d_in[14];
    const float* Wl3  = (const float*)d_in[15];
    const float* bl3  = (const float*)d_in[16];

    const int D = 128;
    const int N = in_sizes[0] / D;           // 50000
    const int E = in_sizes[1] / 2;           // 800000
    const int G = out_size / D;              // 256
    const int H = in_sizes[10];              // 1024
    const int Mpad = ((N + 127) / 128) * 128; // 50048
    const int* row = ei;
    const int* col = ei + E;
    float* out = (float*)d_out;

    char* ws = (char*)d_ws;
    auto alloc = [&](size_t bytes) -> void* {
        void* p = (void*)ws;
        ws += (bytes + 255) & ~(size_t)255;
        return p;
    };
    int*    indeg  = (int*)alloc((size_t)N * 4);
    int*    cursor = (int*)alloc((size_t)N * 4);
    int*    offs   = (int*)alloc((size_t)(N + 1) * 4);
    int*    adj    = (int*)alloc((size_t)E * 4);
    float*  dinv   = (float*)alloc((size_t)N * 4);
    ushort* W1th   = (ushort*)alloc((size_t)256 * 128 * 2);
    ushort* W1tl   = (ushort*)alloc((size_t)256 * 128 * 2);
    ushort* W2th   = (ushort*)alloc((size_t)128 * 256 * 2);
    ushort* W2tl   = (ushort*)alloc((size_t)128 * 256 * 2);
    ushort* yh     = (ushort*)alloc((size_t)Mpad * 128 * 2);   // 12.8 MB
    ushort* yl     = (ushort*)alloc((size_t)Mpad * 128 * 2);   // 12.8 MB
    ushort* out1h  = (ushort*)alloc((size_t)Mpad * 256 * 2);   // 25.6 MB
    ushort* out1l  = (ushort*)alloc((size_t)Mpad * 256 * 2);   // 25.6 MB
    float*  g      = (float*)alloc((size_t)G * 128 * 4);
    float*  m1     = (float*)alloc((size_t)G * 128 * 4);
    float*  g2     = (float*)alloc((size_t)G * H * 4);
    float*  g3     = (float*)alloc((size_t)G * H * 4);
    float*  accb   = (float*)alloc((size_t)G * H * 4);

    // aliases (lifetimes disjoint):
    float* hs2 = (float*)yh;     // [N,128] f32, written by gemm2 after yh/yl dead
    float* y   = (float*)out1h;  // [N,128] f32, written by aggregate2 after out1 dead

    // ---- CSR build + normalization ----
    hipMemsetAsync(indeg, 0, (size_t)N * 4, stream);
    hipMemsetAsync(cursor, 0, (size_t)N * 4, stream);
    count_deg_kernel<<<(E + 255) / 256, 256, 0, stream>>>(col, E, indeg);
    scan_kernel<<<1, 1024, 0, stream>>>(indeg, offs, N);
    dinv_kernel<<<(N + 255) / 256, 256, 0, stream>>>(indeg, dinv, N);
    fill_adj_kernel<<<(E + 255) / 256, 256, 0, stream>>>(row, col, offs, cursor, adj, E);

    // ---- weight transpose + split ----
    transpose_split_kernel<<<(128 * 256 + 255) / 256, 256, 0, stream>>>(W1, W1th, W1tl, 128, 256);
    transpose_split_kernel<<<(256 * 128 + 255) / 256, 256, 0, stream>>>(W2, W2th, W2tl, 256, 128);

    // ---- Layer 1: aggregate (dinv folded) -> bf16 split ----
    aggregate128_kernel<1><<<(N + 3) / 4, 256, 0, stream>>>(
        x, offs, adj, dinv, nullptr, nullptr, yh, yl, N);
    {   // out1(h,l) = split(relu(y @ W1 + b1))   [N,256]
        dim3 grid(Mpad / 128, 256 / 128);
        gemm_bf16x3_kernel<1><<<grid, 256, 0, stream>>>(
            yh, yl, W1th, W1tl, b1, nullptr, nullptr, out1h, out1l, N, 256, 128);
    }

    // ---- Layer 2: hs2 = dinv * (out1 @ W2); aggregate + b2 + relu ----
    {
        dim3 grid(Mpad / 128, 128 / 128);
        gemm_bf16x3_kernel<0><<<grid, 256, 0, stream>>>(
            out1h, out1l, W2th, W2tl, nullptr, dinv, hs2, nullptr, nullptr, N, 128, 256);
    }
    aggregate128_kernel<0><<<(N + 3) / 4, 256, 0, stream>>>(
        hs2, offs, adj, dinv, b2, y, nullptr, nullptr, N);

    // ---- global mean pool ----
    pool_kernel<<<G, 128, 0, stream>>>(y, batch, g, N);

    // ---- MLP (f32 path) ----
    {   // m1 = relu(g @ Wl1 + bl1)        [G,128]
        dim3 grid((G + 63) / 64, 128 / 64);
        gemm_f32_kernel<64, 64, 32, 4, 4><<<grid, 256, 0, stream>>>(
            g, Wl1, m1, nullptr, bl1, G, 128, 128, 128, 1, 0);
    }
    {   // g2 = relu(m1 @ Wl2 + bl2)       [G,1024]
        dim3 grid((G + 63) / 64, H / 64);
        gemm_f32_kernel<64, 64, 32, 4, 4><<<grid, 256, 0, stream>>>(
            m1, Wl2, g2, nullptr, bl2, G, H, 128, 128, 1, 0);
    }
    {   // g3 = relu(g2 @ Wl22 + bl22)     [G,1024] split-K x4
        hipMemsetAsync(accb, 0, (size_t)G * H * 4, stream);
        dim3 grid((G + 63) / 64, H / 64, 4);
        gemm_f32_kernel<64, 64, 32, 4, 4><<<grid, 256, 0, stream>>>(
            g2, Wl22, accb, nullptr, nullptr, G, H, H, 256, 0, 1);
        bias_act_kernel<<<(G * H + 255) / 256, 256, 0, stream>>>(accb, bl22, g3, G * H, H, 1);
    }
    {   // g2 = relu(g3 @ Wl23 + bl23)     [G,1024] split-K x4
        hipMemsetAsync(accb, 0, (size_t)G * H * 4, stream);
        dim3 grid((G + 63) / 64, H / 64, 4);
        gemm_f32_kernel<64, 64, 32, 4, 4><<<grid, 256, 0, stream>>>(
            g3, Wl23, accb, nullptr, nullptr, G, H, H, 256, 0, 1);
        bias_act_kernel<<<(G * H + 255) / 256, 256, 0, stream>>>(accb, bl23, g2, G * H, H, 1);
    }
    {   // out = g2 @ Wl3 + bl3            [G,128] split-K x8
        hipMemsetAsync(m1, 0, (size_t)G * 128 * 4, stream);
        dim3 grid((G + 63) / 64, 128 / 64, 8);
        gemm_f32_kernel<64, 64, 32, 4, 4><<<grid, 256, 0, stream>>>(
            g2, Wl3, m1, nullptr, nullptr, G, 128, H, 128, 0, 1);
        bias_act_kernel<<<(G * 128 + 255) / 256, 256, 0, stream>>>(m1, bl3, out, G * 128, 128, 0);
    }
}

// Round 4
// 490.202 us; speedup vs baseline: 1.4045x; 1.1554x over previous
//
#include <hip/hip_runtime.h>

// ---------------------------------------------------------------------------
// PatternEncoder: 2x GCNConv -> global_mean_pool -> 5-layer MLP
// N=50000, E=800000, D=128, G=256, H=1024
// All GEMMs (node + MLP) use MFMA bf16x3 (C = Ah@Bh + Ah@Bl + Al@Bh).
// Aggregation: pull-based CSR, 8-wide neighbor batching for MLP.
// ---------------------------------------------------------------------------

typedef __attribute__((ext_vector_type(8))) short bf16x8;
typedef __attribute__((ext_vector_type(8))) ushort u16x8;
typedef __attribute__((ext_vector_type(4))) float f32x4;

__device__ __forceinline__ ushort f2bf(float f) {
    unsigned u = __float_as_uint(f);
    unsigned r = (u + 0x7FFFu + ((u >> 16) & 1u)) >> 16;
    return (ushort)r;
}
__device__ __forceinline__ float bf2f(ushort h) {
    return __uint_as_float(((unsigned)h) << 16);
}

// ------------------------------ CSR build ---------------------------------

__global__ void count_deg_kernel(const int* __restrict__ col, int E,
                                 int* __restrict__ indeg) {
    int i = blockIdx.x * blockDim.x + threadIdx.x;
    if (i < E) atomicAdd(&indeg[col[i]], 1);
}

// exclusive scan over indeg -> offs; also writes dinv = rsqrt(deg+1)
__global__ void scan_kernel(const int* __restrict__ indeg, int* __restrict__ offs,
                            float* __restrict__ dinv, int N) {
    __shared__ int sm[1024];
    int tid = threadIdx.x;
    int chunk = (N + 1023) / 1024;
    int s = tid * chunk;
    int e = s + chunk; if (e > N) e = N; if (s > N) s = N;
    int sum = 0;
    for (int i = s; i < e; ++i) sum += indeg[i];
    sm[tid] = sum;
    __syncthreads();
    int val = sum;
    for (int off = 1; off < 1024; off <<= 1) {
        int t = (tid >= off) ? sm[tid - off] : 0;
        __syncthreads();
        val += t;
        sm[tid] = val;
        __syncthreads();
    }
    int prefix = val - sum;
    for (int i = s; i < e; ++i) {
        int d = indeg[i];
        offs[i] = prefix; prefix += d;
        dinv[i] = rsqrtf((float)(d + 1));
    }
    if (tid == 1023) offs[N] = prefix;
}

__global__ void fill_adj_kernel(const int* __restrict__ row, const int* __restrict__ col,
                                const int* __restrict__ offs, int* __restrict__ cursor,
                                int* __restrict__ adj, int E) {
    int e = blockIdx.x * blockDim.x + threadIdx.x;
    if (e < E) {
        int c = col[e];
        int pos = atomicAdd(&cursor[c], 1);
        adj[offs[c] + pos] = row[e];
    }
}

// ---------------- weight transpose+split (LDS-tiled, coalesced) -------------
// W [K][Nn] f32 -> Th,Tl [Nn][K] bf16. 64x64 tiles, grid (K/64, Nn/64).
__global__ __launch_bounds__(256) void tsplit_kernel(
        const float* __restrict__ W, ushort* __restrict__ Th, ushort* __restrict__ Tl,
        int K, int Nn) {
    __shared__ float sm[64][65];
    int k0 = blockIdx.x * 64, n0 = blockIdx.y * 64;
    int tid = threadIdx.x;
    int r = tid >> 2, cq = tid & 3;          // row, 16-col chunk
#pragma unroll
    for (int i = 0; i < 4; ++i) {
        float4 v = *(const float4*)(W + (size_t)(k0 + r) * Nn + n0 + cq * 16 + i * 4);
        sm[r][cq * 16 + i * 4 + 0] = v.x;
        sm[r][cq * 16 + i * 4 + 1] = v.y;
        sm[r][cq * 16 + i * 4 + 2] = v.z;
        sm[r][cq * 16 + i * 4 + 3] = v.w;
    }
    __syncthreads();
    int n = tid >> 2, kq = tid & 3;          // out row (n), 16-k chunk
    ushort h[16], l[16];
#pragma unroll
    for (int i = 0; i < 16; ++i) {
        float v = sm[kq * 16 + i][n];
        h[i] = f2bf(v);
        l[i] = f2bf(v - bf2f(h[i]));
    }
    size_t o = (size_t)(n0 + n) * K + k0 + kq * 16;
    *(u16x8*)(&Th[o]) = *(u16x8*)&h[0];
    *(u16x8*)(&Th[o + 8]) = *(u16x8*)&h[8];
    *(u16x8*)(&Tl[o]) = *(u16x8*)&l[0];
    *(u16x8*)(&Tl[o + 8]) = *(u16x8*)&l[8];
}

// ------------------------------ aggregation --------------------------------
// MODE 1 (layer 1): out = dinv[i]*(sum dinv[src]*x[src] + dinv[i]*x[i]); bf16 hi/lo
// MODE 0 (layer 2): out = relu(dinv[i]*(sum hs[src] + hs[i]) + bias);    f32
// one wave per node, float2/lane, 8-wide neighbor batching for MLP.
template<int MODE>
__global__ void aggregate128_kernel(const float* __restrict__ hs,
                                    const int* __restrict__ offs,
                                    const int* __restrict__ adj,
                                    const float* __restrict__ dinv,
                                    const float* __restrict__ bias,
                                    float* __restrict__ outf,
                                    ushort* __restrict__ outh, ushort* __restrict__ outl,
                                    int N) {
    int wid = (blockIdx.x * blockDim.x + threadIdx.x) >> 6;
    int lane = threadIdx.x & 63;
    if (wid >= N) return;
    const float2* base = (const float2*)hs;
    float dself = dinv[wid];
    float2 a = base[(size_t)wid * 64 + lane];
    float ax, ay;
    if (MODE == 1) { ax = a.x * dself; ay = a.y * dself; }
    else           { ax = a.x;         ay = a.y; }
    int s = offs[wid], e = offs[wid + 1];
    for (int j = s; j < e; j += 8) {
        int idx[8]; float w[8];
#pragma unroll
        for (int k = 0; k < 8; ++k) {
            int jj = j + k;
            bool valid = jj < e;
            idx[k] = adj[valid ? jj : s];
            w[k] = valid ? 1.f : 0.f;
        }
        float2 v[8];
#pragma unroll
        for (int k = 0; k < 8; ++k) v[k] = base[(size_t)idx[k] * 64 + lane];
        if (MODE == 1) {
#pragma unroll
            for (int k = 0; k < 8; ++k) w[k] *= dinv[idx[k]];
        }
#pragma unroll
        for (int k = 0; k < 8; ++k) {
            ax = fmaf(w[k], v[k].x, ax);
            ay = fmaf(w[k], v[k].y, ay);
        }
    }
    ax *= dself; ay *= dself;
    if (MODE == 0) {
        float2 b = ((const float2*)bias)[lane];
        ax = fmaxf(ax + b.x, 0.f); ay = fmaxf(ay + b.y, 0.f);
        ((float2*)outf)[(size_t)wid * 64 + lane] = make_float2(ax, ay);
    } else {
        ushort h0 = f2bf(ax), h1 = f2bf(ay);
        ushort l0 = f2bf(ax - bf2f(h0)), l1 = f2bf(ay - bf2f(h1));
        ((ushort2*)outh)[(size_t)wid * 64 + lane] = make_ushort2(h0, h1);
        ((ushort2*)outl)[(size_t)wid * 64 + lane] = make_ushort2(l0, l1);
    }
}

// --------------------------- MFMA bf16x3 GEMM ------------------------------
// C[M,N] = A[M,K] @ B[K,N]; A = (Ah,Al) bf16 [M,K]; B = (Bth,Btl) bf16 [N][K].
// Tile BMxBM, BK=32, 4 waves (2x2). BM=128: 64x64/wave; BM=64: 32x32/wave.
// EPI 0: v *= rowscale[row]; f32 out
// EPI 1: v = relu(v + bias[col]); bf16 hi/lo out
// EPI 2: v += bias[col]; f32 out
#define SWZ(r) (((r) >> 1) & 3)

template<int BM, int EPI>
__global__ __launch_bounds__(256) void gemm_bf16x3_kernel(
        const ushort* __restrict__ Ah, const ushort* __restrict__ Al,
        const ushort* __restrict__ Bth, const ushort* __restrict__ Btl,
        const float* __restrict__ bias, const float* __restrict__ rowscale,
        float* __restrict__ Cf, ushort* __restrict__ Ch, ushort* __restrict__ Cl,
        int M, int N, int K) {
    constexpr int WM = BM / 2;       // wave tile
    constexpr int FR = WM / 16;      // frags per dim
    constexpr int NV = BM / 64;      // staging issues per tile
    __shared__ __align__(16) ushort lds[4][BM][32];

    const int tid = threadIdx.x;
    const int w = tid >> 6, lane = tid & 63;
    const int wr = w >> 1, wc = w & 1;
    const int bm = blockIdx.x * BM, bn = blockIdx.y * BM;

    const ushort* srcs[4] = {
        Ah  + (size_t)bm * K, Al  + (size_t)bm * K,
        Bth + (size_t)bn * K, Btl + (size_t)bn * K };

    f32x4 acc[FR][FR];
#pragma unroll
    for (int i = 0; i < FR; ++i)
#pragma unroll
        for (int j = 0; j < FR; ++j) acc[i][j] = (f32x4)0.f;

    const int s = lane >> 4, r16 = lane & 15;

    for (int k0 = 0; k0 < K; k0 += 32) {
#pragma unroll
        for (int t = 0; t < 4; ++t) {
#pragma unroll
            for (int v = 0; v < NV; ++v) {
                int chunk = v * 4 + w;
                int row = chunk * 16 + (lane >> 2);
                int u = lane & 3;
                int col = k0 + 8 * (u ^ SWZ(row));
                const ushort* g = srcs[t] + (size_t)row * K + col;
                ushort* l = &lds[t][chunk * 16][0];
                __builtin_amdgcn_global_load_lds(
                    (const __attribute__((address_space(1))) void*)g,
                    (__attribute__((address_space(3))) void*)l, 16, 0, 0);
            }
        }
        __syncthreads();

        bf16x8 ah[FR], al[FR], bh[FR], bl[FR];
#pragma unroll
        for (int f = 0; f < FR; ++f) {
            int ra = wr * WM + f * 16 + r16;
            int oa = ra * 64 + 16 * (s ^ SWZ(ra));
            ah[f] = *(const bf16x8*)((const char*)&lds[0][0][0] + oa);
            al[f] = *(const bf16x8*)((const char*)&lds[1][0][0] + oa);
            int rb = wc * WM + f * 16 + r16;
            int ob = rb * 64 + 16 * (s ^ SWZ(rb));
            bh[f] = *(const bf16x8*)((const char*)&lds[2][0][0] + ob);
            bl[f] = *(const bf16x8*)((const char*)&lds[3][0][0] + ob);
        }

#pragma unroll
        for (int i = 0; i < FR; ++i)
#pragma unroll
            for (int j = 0; j < FR; ++j) {
                acc[i][j] = __builtin_amdgcn_mfma_f32_16x16x32_bf16(ah[i], bh[j], acc[i][j], 0, 0, 0);
                acc[i][j] = __builtin_amdgcn_mfma_f32_16x16x32_bf16(ah[i], bl[j], acc[i][j], 0, 0, 0);
                acc[i][j] = __builtin_amdgcn_mfma_f32_16x16x32_bf16(al[i], bh[j], acc[i][j], 0, 0, 0);
            }
        __syncthreads();
    }

    // C/D layout: col=lane&15, row=(lane>>4)*4+reg (m89-verified)
    const int q4 = lane >> 4;
#pragma unroll
    for (int i = 0; i < FR; ++i) {
        int row0 = bm + wr * WM + i * 16 + q4 * 4;
        if (row0 >= M) continue;
#pragma unroll
        for (int j = 0; j < FR; ++j) {
            int colc = bn + wc * WM + j * 16 + r16;
            if (EPI == 1) {
                float bv = bias[colc];
#pragma unroll
                for (int r = 0; r < 4; ++r) {
                    float v = fmaxf(acc[i][j][r] + bv, 0.f);
                    ushort h = f2bf(v);
                    ushort lo = f2bf(v - bf2f(h));
                    size_t o = (size_t)(row0 + r) * N + colc;
                    Ch[o] = h; Cl[o] = lo;
                }
            } else if (EPI == 0) {
#pragma unroll
                for (int r = 0; r < 4; ++r) {
                    float v = acc[i][j][r] * rowscale[row0 + r];
                    Cf[(size_t)(row0 + r) * N + colc] = v;
                }
            } else {
                float bv = bias[colc];
#pragma unroll
                for (int r = 0; r < 4; ++r) {
                    float v = acc[i][j][r] + bv;
                    Cf[(size_t)(row0 + r) * N + colc] = v;
                }
            }
        }
    }
}

// ------------------------------- pooling -----------------------------------
// one block (256 thr) per graph; 2 rows in flight; emits bf16 hi/lo
__global__ void pool_kernel(const float* __restrict__ feats, const int* __restrict__ batch,
                            ushort* __restrict__ gh, ushort* __restrict__ gl, int N) {
    __shared__ float sm[256];
    int gid = blockIdx.x;
    int lo = 0, hi = N;
    while (lo < hi) { int m = (lo + hi) >> 1; if (batch[m] < gid) lo = m + 1; else hi = m; }
    int start = lo;
    lo = start; hi = N;
    while (lo < hi) { int m = (lo + hi) >> 1; if (batch[m] < gid + 1) lo = m + 1; else hi = m; }
    int end = lo;
    int tid = threadIdx.x;
    int f = tid & 127, half = tid >> 7;
    float acc = 0.f;
    for (int i = start + half; i < end; i += 2) acc += feats[(size_t)i * 128 + f];
    sm[tid] = acc;
    __syncthreads();
    if (half == 0) {
        acc += sm[tid + 128];
        int cnt = end - start; if (cnt < 1) cnt = 1;
        float m = acc / (float)cnt;
        ushort h = f2bf(m);
        gh[gid * 128 + f] = h;
        gl[gid * 128 + f] = f2bf(m - bf2f(h));
    }
}

// ---------------------------------------------------------------------------

extern "C" void kernel_launch(void* const* d_in, const int* in_sizes, int n_in,
                              void* d_out, int out_size, void* d_ws, size_t ws_size,
                              hipStream_t stream) {
    const float* x    = (const float*)d_in[0];
    const int*   ei   = (const int*)d_in[1];
    const int*   batch= (const int*)d_in[2];
    const float* W1   = (const float*)d_in[3];
    const float* b1   = (const float*)d_in[4];
    const float* W2   = (const float*)d_in[5];
    const float* b2   = (const float*)d_in[6];
    const float* Wl1  = (const float*)d_in[7];
    const float* bl1  = (const float*)d_in[8];
    const float* Wl2  = (const float*)d_in[9];
    const float* bl2  = (const float*)d_in[10];
    const float* Wl22 = (const float*)d_in[11];
    const float* bl22 = (const float*)d_in[12];
    const float* Wl23 = (const float*)d_in[13];
    const float* bl23 = (const float*)d_in[14];
    const float* Wl3  = (const float*)d_in[15];
    const float* bl3  = (const float*)d_in[16];

    const int D = 128;
    const int N = in_sizes[0] / D;            // 50000
    const int E = in_sizes[1] / 2;            // 800000
    const int G = out_size / D;               // 256
    const int H = in_sizes[10];               // 1024
    const int Mpad = ((N + 127) / 128) * 128; // 50048
    const int* row = ei;
    const int* col = ei + E;
    float* out = (float*)d_out;

    char* ws = (char*)d_ws;
    auto alloc = [&](size_t bytes) -> void* {
        void* p = (void*)ws;
        ws += (bytes + 255) & ~(size_t)255;
        return p;
    };
    int*    indeg  = (int*)alloc((size_t)N * 4);
    int*    cursor = (int*)alloc((size_t)N * 4);
    int*    offs   = (int*)alloc((size_t)(N + 1) * 4);
    int*    adj    = (int*)alloc((size_t)E * 4);
    float*  dinv   = (float*)alloc((size_t)N * 4);
    // node-GEMM weights (transposed+split)
    ushort* W1th   = (ushort*)alloc((size_t)256 * 128 * 2);
    ushort* W1tl   = (ushort*)alloc((size_t)256 * 128 * 2);
    ushort* W2th   = (ushort*)alloc((size_t)128 * 256 * 2);
    ushort* W2tl   = (ushort*)alloc((size_t)128 * 256 * 2);
    // MLP weights (transposed+split)
    ushort* Tl1h  = (ushort*)alloc((size_t)128 * 128 * 2);
    ushort* Tl1l  = (ushort*)alloc((size_t)128 * 128 * 2);
    ushort* Tl2h  = (ushort*)alloc((size_t)H * 128 * 2);
    ushort* Tl2l  = (ushort*)alloc((size_t)H * 128 * 2);
    ushort* Tl22h = (ushort*)alloc((size_t)H * H * 2);
    ushort* Tl22l = (ushort*)alloc((size_t)H * H * 2);
    ushort* Tl23h = (ushort*)alloc((size_t)H * H * 2);
    ushort* Tl23l = (ushort*)alloc((size_t)H * H * 2);
    ushort* Tl3h  = (ushort*)alloc((size_t)128 * H * 2);
    ushort* Tl3l  = (ushort*)alloc((size_t)128 * H * 2);
    // activations
    ushort* yh     = (ushort*)alloc((size_t)Mpad * 128 * 2);   // 12.8 MB
    ushort* yl     = (ushort*)alloc((size_t)Mpad * 128 * 2);   // 12.8 MB
    ushort* out1h  = (ushort*)alloc((size_t)Mpad * 256 * 2);   // 25.6 MB
    ushort* out1l  = (ushort*)alloc((size_t)Mpad * 256 * 2);   // 25.6 MB
    ushort* gh     = (ushort*)alloc((size_t)G * 128 * 2);
    ushort* gl     = (ushort*)alloc((size_t)G * 128 * 2);
    ushort* a1h    = (ushort*)alloc((size_t)G * 128 * 2);
    ushort* a1l    = (ushort*)alloc((size_t)G * 128 * 2);
    ushort* a2h    = (ushort*)alloc((size_t)G * H * 2);
    ushort* a2l    = (ushort*)alloc((size_t)G * H * 2);
    ushort* a3h    = (ushort*)alloc((size_t)G * H * 2);
    ushort* a3l    = (ushort*)alloc((size_t)G * H * 2);
    ushort* a4h    = (ushort*)alloc((size_t)G * H * 2);
    ushort* a4l    = (ushort*)alloc((size_t)G * H * 2);

    // aliases (lifetimes disjoint):
    float* hs2 = (float*)yh;     // [N,128] f32 spans yh+yl (both dead after gemm1)
    float* y   = (float*)out1h;  // [N,128] f32 spans out1h (dead after gemm2)

    // ---- CSR build + normalization ----
    hipMemsetAsync(indeg, 0, (size_t)N * 4, stream);
    hipMemsetAsync(cursor, 0, (size_t)N * 4, stream);
    count_deg_kernel<<<(E + 255) / 256, 256, 0, stream>>>(col, E, indeg);
    scan_kernel<<<1, 1024, 0, stream>>>(indeg, offs, dinv, N);
    fill_adj_kernel<<<(E + 255) / 256, 256, 0, stream>>>(row, col, offs, cursor, adj, E);

    // ---- weight transpose + split ----
    tsplit_kernel<<<dim3(128 / 64, 256 / 64), 256, 0, stream>>>(W1, W1th, W1tl, 128, 256);
    tsplit_kernel<<<dim3(256 / 64, 128 / 64), 256, 0, stream>>>(W2, W2th, W2tl, 256, 128);
    tsplit_kernel<<<dim3(128 / 64, 128 / 64), 256, 0, stream>>>(Wl1, Tl1h, Tl1l, 128, 128);
    tsplit_kernel<<<dim3(128 / 64, H / 64), 256, 0, stream>>>(Wl2, Tl2h, Tl2l, 128, H);
    tsplit_kernel<<<dim3(H / 64, H / 64), 256, 0, stream>>>(Wl22, Tl22h, Tl22l, H, H);
    tsplit_kernel<<<dim3(H / 64, H / 64), 256, 0, stream>>>(Wl23, Tl23h, Tl23l, H, H);
    tsplit_kernel<<<dim3(H / 64, 128 / 64), 256, 0, stream>>>(Wl3, Tl3h, Tl3l, H, 128);

    // ---- Layer 1: aggregate (dinv folded) -> bf16 split ----
    aggregate128_kernel<1><<<(N + 3) / 4, 256, 0, stream>>>(
        x, offs, adj, dinv, nullptr, nullptr, yh, yl, N);
    {   // out1(h,l) = split(relu(y @ W1 + b1))   [N,256]
        dim3 grid(Mpad / 128, 256 / 128);
        gemm_bf16x3_kernel<128, 1><<<grid, 256, 0, stream>>>(
            yh, yl, W1th, W1tl, b1, nullptr, nullptr, out1h, out1l, N, 256, 128);
    }

    // ---- Layer 2: hs2 = dinv * (out1 @ W2); aggregate + b2 + relu ----
    {
        dim3 grid(Mpad / 128, 1);
        gemm_bf16x3_kernel<128, 0><<<grid, 256, 0, stream>>>(
            out1h, out1l, W2th, W2tl, nullptr, dinv, hs2, nullptr, nullptr, N, 128, 256);
    }
    aggregate128_kernel<0><<<(N + 3) / 4, 256, 0, stream>>>(
        hs2, offs, adj, dinv, b2, y, nullptr, nullptr, N);

    // ---- global mean pool (emits bf16 hi/lo) ----
    pool_kernel<<<G, 256, 0, stream>>>(y, batch, gh, gl, N);

    // ---- MLP (all MFMA bf16x3, BM=64) ----
    {   // a1 = relu(g @ Wl1 + bl1)        [G,128]
        dim3 grid(G / 64, 128 / 64);
        gemm_bf16x3_kernel<64, 1><<<grid, 256, 0, stream>>>(
            gh, gl, Tl1h, Tl1l, bl1, nullptr, nullptr, a1h, a1l, G, 128, 128);
    }
    {   // a2 = relu(a1 @ Wl2 + bl2)       [G,1024]
        dim3 grid(G / 64, H / 64);
        gemm_bf16x3_kernel<64, 1><<<grid, 256, 0, stream>>>(
            a1h, a1l, Tl2h, Tl2l, bl2, nullptr, nullptr, a2h, a2l, G, H, 128);
    }
    {   // a3 = relu(a2 @ Wl22 + bl22)     [G,1024]
        dim3 grid(G / 64, H / 64);
        gemm_bf16x3_kernel<64, 1><<<grid, 256, 0, stream>>>(
            a2h, a2l, Tl22h, Tl22l, bl22, nullptr, nullptr, a3h, a3l, G, H, H);
    }
    {   // a4 = relu(a3 @ Wl23 + bl23)     [G,1024]
        dim3 grid(G / 64, H / 64);
        gemm_bf16x3_kernel<64, 1><<<grid, 256, 0, stream>>>(
            a3h, a3l, Tl23h, Tl23l, bl23, nullptr, nullptr, a4h, a4l, G, H, H);
    }
    {   // out = a4 @ Wl3 + bl3            [G,128] f32
        dim3 grid(G / 64, 128 / 64);
        gemm_bf16x3_kernel<64, 2><<<grid, 256, 0, stream>>>(
            a4h, a4l, Tl3h, Tl3l, bl3, nullptr, out, nullptr, nullptr, G, 128, H);
    }
}

// Round 5
// 390.717 us; speedup vs baseline: 1.7621x; 1.2546x over previous
//
#include <hip/hip_runtime.h>

// ---------------------------------------------------------------------------
// PatternEncoder: 2x GCNConv -> global_mean_pool -> 5-layer MLP
// N=50000, E=800000, D=128, G=256, H=1024
// All GEMMs (node + MLP) use MFMA bf16x3 (C = Ah@Bh + Ah@Bl + Al@Bh).
// Aggregation: pull-based CSR, 8-wide neighbor batching.
// CSR offsets via 3-phase multi-block scan (round 4's single-block scan was
// a 107 us serialization).
// ---------------------------------------------------------------------------

typedef __attribute__((ext_vector_type(8))) short bf16x8;
typedef __attribute__((ext_vector_type(8))) ushort u16x8;
typedef __attribute__((ext_vector_type(4))) float f32x4;

__device__ __forceinline__ ushort f2bf(float f) {
    unsigned u = __float_as_uint(f);
    unsigned r = (u + 0x7FFFu + ((u >> 16) & 1u)) >> 16;
    return (ushort)r;
}
__device__ __forceinline__ float bf2f(ushort h) {
    return __uint_as_float(((unsigned)h) << 16);
}

// ------------------------------ CSR build ---------------------------------

__global__ void count_deg_kernel(const int* __restrict__ col, int E,
                                 int* __restrict__ indeg) {
    int i = blockIdx.x * blockDim.x + threadIdx.x;
    if (i < E) atomicAdd(&indeg[col[i]], 1);
}

// phase 1: per-block (1024 elems) partial sums
__global__ void scan_p1_kernel(const int* __restrict__ indeg, int* __restrict__ bsum,
                               int N) {
    __shared__ int sm[256];
    int b = blockIdx.x, tid = threadIdx.x;
    int base = b * 1024 + tid * 4;
    int sum = 0;
    if (base + 4 <= N) {
        int4 v = *(const int4*)(indeg + base);
        sum = v.x + v.y + v.z + v.w;
    } else {
        for (int i = 0; i < 4; ++i) if (base + i < N) sum += indeg[base + i];
    }
    sm[tid] = sum;
    __syncthreads();
    for (int off = 128; off > 0; off >>= 1) {
        if (tid < off) sm[tid] += sm[tid + off];
        __syncthreads();
    }
    if (tid == 0) bsum[b] = sm[0];
}

// phase 2: single small block scans the <=1024 block sums (exclusive, in place)
__global__ void scan_p2_kernel(int* __restrict__ bsum, int nb) {
    __shared__ int sm[1024];
    int tid = threadIdx.x;
    int v = (tid < nb) ? bsum[tid] : 0;
    sm[tid] = v;
    __syncthreads();
    int val = v;
    for (int off = 1; off < 1024; off <<= 1) {
        int t = (tid >= off) ? sm[tid - off] : 0;
        __syncthreads();
        val += t;
        sm[tid] = val;
        __syncthreads();
    }
    if (tid < nb) bsum[tid] = val - v;
}

// phase 3: per-block exclusive scan; writes offs, dinv, and offs[N]
__global__ void scan_p3_kernel(const int* __restrict__ indeg, const int* __restrict__ bsum,
                               int* __restrict__ offs, float* __restrict__ dinv, int N) {
    __shared__ int sm[256];
    int b = blockIdx.x, tid = threadIdx.x;
    int base = b * 1024 + tid * 4;
    int d[4];
    int sum = 0;
    if (base + 4 <= N) {
        int4 v = *(const int4*)(indeg + base);
        d[0] = v.x; d[1] = v.y; d[2] = v.z; d[3] = v.w;
        sum = v.x + v.y + v.z + v.w;
    } else {
#pragma unroll
        for (int i = 0; i < 4; ++i) {
            d[i] = (base + i < N) ? indeg[base + i] : 0;
            sum += d[i];
        }
    }
    sm[tid] = sum;
    __syncthreads();
    int val = sum;
    for (int off = 1; off < 256; off <<= 1) {
        int t = (tid >= off) ? sm[tid - off] : 0;
        __syncthreads();
        val += t;
        sm[tid] = val;
        __syncthreads();
    }
    int prefix = bsum[b] + val - sum;
#pragma unroll
    for (int i = 0; i < 4; ++i) {
        int idx = base + i;
        if (idx < N) {
            offs[idx] = prefix;
            dinv[idx] = rsqrtf((float)(d[i] + 1));
            prefix += d[i];
            if (idx == N - 1) offs[N] = prefix;
        }
    }
}

__global__ void fill_adj_kernel(const int* __restrict__ row, const int* __restrict__ col,
                                const int* __restrict__ offs, int* __restrict__ cursor,
                                int* __restrict__ adj, int E) {
    int e = blockIdx.x * blockDim.x + threadIdx.x;
    if (e < E) {
        int c = col[e];
        int pos = atomicAdd(&cursor[c], 1);
        adj[offs[c] + pos] = row[e];
    }
}

// ---------------- weight transpose+split (LDS-tiled, coalesced) -------------
// W [K][Nn] f32 -> Th,Tl [Nn][K] bf16. 64x64 tiles, grid (K/64, Nn/64).
__global__ __launch_bounds__(256) void tsplit_kernel(
        const float* __restrict__ W, ushort* __restrict__ Th, ushort* __restrict__ Tl,
        int K, int Nn) {
    __shared__ float sm[64][65];
    int k0 = blockIdx.x * 64, n0 = blockIdx.y * 64;
    int tid = threadIdx.x;
    int r = tid >> 2, cq = tid & 3;          // row, 16-col chunk
#pragma unroll
    for (int i = 0; i < 4; ++i) {
        float4 v = *(const float4*)(W + (size_t)(k0 + r) * Nn + n0 + cq * 16 + i * 4);
        sm[r][cq * 16 + i * 4 + 0] = v.x;
        sm[r][cq * 16 + i * 4 + 1] = v.y;
        sm[r][cq * 16 + i * 4 + 2] = v.z;
        sm[r][cq * 16 + i * 4 + 3] = v.w;
    }
    __syncthreads();
    int n = tid >> 2, kq = tid & 3;          // out row (n), 16-k chunk
    ushort h[16], l[16];
#pragma unroll
    for (int i = 0; i < 16; ++i) {
        float v = sm[kq * 16 + i][n];
        h[i] = f2bf(v);
        l[i] = f2bf(v - bf2f(h[i]));
    }
    size_t o = (size_t)(n0 + n) * K + k0 + kq * 16;
    *(u16x8*)(&Th[o]) = *(u16x8*)&h[0];
    *(u16x8*)(&Th[o + 8]) = *(u16x8*)&h[8];
    *(u16x8*)(&Tl[o]) = *(u16x8*)&l[0];
    *(u16x8*)(&Tl[o + 8]) = *(u16x8*)&l[8];
}

// ------------------------------ aggregation --------------------------------
// MODE 1 (layer 1): out = dinv[i]*(sum dinv[src]*x[src] + dinv[i]*x[i]); bf16 hi/lo
// MODE 0 (layer 2): out = relu(dinv[i]*(sum hs[src] + hs[i]) + bias);    f32
// one wave per node, float2/lane, 8-wide neighbor batching.
template<int MODE>
__global__ void aggregate128_kernel(const float* __restrict__ hs,
                                    const int* __restrict__ offs,
                                    const int* __restrict__ adj,
                                    const float* __restrict__ dinv,
                                    const float* __restrict__ bias,
                                    float* __restrict__ outf,
                                    ushort* __restrict__ outh, ushort* __restrict__ outl,
                                    int N) {
    int wid = (blockIdx.x * blockDim.x + threadIdx.x) >> 6;
    int lane = threadIdx.x & 63;
    if (wid >= N) return;
    const float2* base = (const float2*)hs;
    float dself = dinv[wid];
    float2 a = base[(size_t)wid * 64 + lane];
    float ax, ay;
    if (MODE == 1) { ax = a.x * dself; ay = a.y * dself; }
    else           { ax = a.x;         ay = a.y; }
    int s = offs[wid], e = offs[wid + 1];
    for (int j = s; j < e; j += 8) {
        int idx[8]; float w[8];
#pragma unroll
        for (int k = 0; k < 8; ++k) {
            int jj = j + k;
            bool valid = jj < e;
            idx[k] = adj[valid ? jj : s];
            w[k] = valid ? 1.f : 0.f;
        }
        float2 v[8];
#pragma unroll
        for (int k = 0; k < 8; ++k) v[k] = base[(size_t)idx[k] * 64 + lane];
        if (MODE == 1) {
#pragma unroll
            for (int k = 0; k < 8; ++k) w[k] *= dinv[idx[k]];
        }
#pragma unroll
        for (int k = 0; k < 8; ++k) {
            ax = fmaf(w[k], v[k].x, ax);
            ay = fmaf(w[k], v[k].y, ay);
        }
    }
    ax *= dself; ay *= dself;
    if (MODE == 0) {
        float2 b = ((const float2*)bias)[lane];
        ax = fmaxf(ax + b.x, 0.f); ay = fmaxf(ay + b.y, 0.f);
        ((float2*)outf)[(size_t)wid * 64 + lane] = make_float2(ax, ay);
    } else {
        ushort h0 = f2bf(ax), h1 = f2bf(ay);
        ushort l0 = f2bf(ax - bf2f(h0)), l1 = f2bf(ay - bf2f(h1));
        ((ushort2*)outh)[(size_t)wid * 64 + lane] = make_ushort2(h0, h1);
        ((ushort2*)outl)[(size_t)wid * 64 + lane] = make_ushort2(l0, l1);
    }
}

// --------------------------- MFMA bf16x3 GEMM ------------------------------
// C[M,N] = A[M,K] @ B[K,N]; A = (Ah,Al) bf16 [M,K]; B = (Bth,Btl) bf16 [N][K].
// Tile BMxBM, BK=32, 4 waves (2x2). BM=128: 64x64/wave; BM=64: 32x32/wave.
// EPI 0: v *= rowscale[row]; f32 out
// EPI 1: v = relu(v + bias[col]); bf16 hi/lo out
// EPI 2: v += bias[col]; f32 out
#define SWZ(r) (((r) >> 1) & 3)

template<int BM, int EPI>
__global__ __launch_bounds__(256) void gemm_bf16x3_kernel(
        const ushort* __restrict__ Ah, const ushort* __restrict__ Al,
        const ushort* __restrict__ Bth, const ushort* __restrict__ Btl,
        const float* __restrict__ bias, const float* __restrict__ rowscale,
        float* __restrict__ Cf, ushort* __restrict__ Ch, ushort* __restrict__ Cl,
        int M, int N, int K) {
    constexpr int WM = BM / 2;       // wave tile
    constexpr int FR = WM / 16;      // frags per dim
    constexpr int NV = BM / 64;      // staging issues per tile
    __shared__ __align__(16) ushort lds[4][BM][32];

    const int tid = threadIdx.x;
    const int w = tid >> 6, lane = tid & 63;
    const int wr = w >> 1, wc = w & 1;
    const int bm = blockIdx.x * BM, bn = blockIdx.y * BM;

    const ushort* srcs[4] = {
        Ah  + (size_t)bm * K, Al  + (size_t)bm * K,
        Bth + (size_t)bn * K, Btl + (size_t)bn * K };

    f32x4 acc[FR][FR];
#pragma unroll
    for (int i = 0; i < FR; ++i)
#pragma unroll
        for (int j = 0; j < FR; ++j) acc[i][j] = (f32x4)0.f;

    const int s = lane >> 4, r16 = lane & 15;

    for (int k0 = 0; k0 < K; k0 += 32) {
#pragma unroll
        for (int t = 0; t < 4; ++t) {
#pragma unroll
            for (int v = 0; v < NV; ++v) {
                int chunk = v * 4 + w;
                int row = chunk * 16 + (lane >> 2);
                int u = lane & 3;
                int col = k0 + 8 * (u ^ SWZ(row));
                const ushort* g = srcs[t] + (size_t)row * K + col;
                ushort* l = &lds[t][chunk * 16][0];
                __builtin_amdgcn_global_load_lds(
                    (const __attribute__((address_space(1))) void*)g,
                    (__attribute__((address_space(3))) void*)l, 16, 0, 0);
            }
        }
        __syncthreads();

        bf16x8 ah[FR], al[FR], bh[FR], bl[FR];
#pragma unroll
        for (int f = 0; f < FR; ++f) {
            int ra = wr * WM + f * 16 + r16;
            int oa = ra * 64 + 16 * (s ^ SWZ(ra));
            ah[f] = *(const bf16x8*)((const char*)&lds[0][0][0] + oa);
            al[f] = *(const bf16x8*)((const char*)&lds[1][0][0] + oa);
            int rb = wc * WM + f * 16 + r16;
            int ob = rb * 64 + 16 * (s ^ SWZ(rb));
            bh[f] = *(const bf16x8*)((const char*)&lds[2][0][0] + ob);
            bl[f] = *(const bf16x8*)((const char*)&lds[3][0][0] + ob);
        }

#pragma unroll
        for (int i = 0; i < FR; ++i)
#pragma unroll
            for (int j = 0; j < FR; ++j) {
                acc[i][j] = __builtin_amdgcn_mfma_f32_16x16x32_bf16(ah[i], bh[j], acc[i][j], 0, 0, 0);
                acc[i][j] = __builtin_amdgcn_mfma_f32_16x16x32_bf16(ah[i], bl[j], acc[i][j], 0, 0, 0);
                acc[i][j] = __builtin_amdgcn_mfma_f32_16x16x32_bf16(al[i], bh[j], acc[i][j], 0, 0, 0);
            }
        __syncthreads();
    }

    // C/D layout: col=lane&15, row=(lane>>4)*4+reg (m89-verified)
    const int q4 = lane >> 4;
#pragma unroll
    for (int i = 0; i < FR; ++i) {
        int row0 = bm + wr * WM + i * 16 + q4 * 4;
        if (row0 >= M) continue;
#pragma unroll
        for (int j = 0; j < FR; ++j) {
            int colc = bn + wc * WM + j * 16 + r16;
            if (EPI == 1) {
                float bv = bias[colc];
#pragma unroll
                for (int r = 0; r < 4; ++r) {
                    float v = fmaxf(acc[i][j][r] + bv, 0.f);
                    ushort h = f2bf(v);
                    ushort lo = f2bf(v - bf2f(h));
                    size_t o = (size_t)(row0 + r) * N + colc;
                    Ch[o] = h; Cl[o] = lo;
                }
            } else if (EPI == 0) {
#pragma unroll
                for (int r = 0; r < 4; ++r) {
                    float v = acc[i][j][r] * rowscale[row0 + r];
                    Cf[(size_t)(row0 + r) * N + colc] = v;
                }
            } else {
                float bv = bias[colc];
#pragma unroll
                for (int r = 0; r < 4; ++r) {
                    float v = acc[i][j][r] + bv;
                    Cf[(size_t)(row0 + r) * N + colc] = v;
                }
            }
        }
    }
}

// ------------------------------- pooling -----------------------------------
// one block (256 thr) per graph; 2 rows in flight; emits bf16 hi/lo
__global__ void pool_kernel(const float* __restrict__ feats, const int* __restrict__ batch,
                            ushort* __restrict__ gh, ushort* __restrict__ gl, int N) {
    __shared__ float sm[256];
    int gid = blockIdx.x;
    int lo = 0, hi = N;
    while (lo < hi) { int m = (lo + hi) >> 1; if (batch[m] < gid) lo = m + 1; else hi = m; }
    int start = lo;
    lo = start; hi = N;
    while (lo < hi) { int m = (lo + hi) >> 1; if (batch[m] < gid + 1) lo = m + 1; else hi = m; }
    int end = lo;
    int tid = threadIdx.x;
    int f = tid & 127, half = tid >> 7;
    float acc = 0.f;
    for (int i = start + half; i < end; i += 2) acc += feats[(size_t)i * 128 + f];
    sm[tid] = acc;
    __syncthreads();
    if (half == 0) {
        acc += sm[tid + 128];
        int cnt = end - start; if (cnt < 1) cnt = 1;
        float m = acc / (float)cnt;
        ushort h = f2bf(m);
        gh[gid * 128 + f] = h;
        gl[gid * 128 + f] = f2bf(m - bf2f(h));
    }
}

// ---------------------------------------------------------------------------

extern "C" void kernel_launch(void* const* d_in, const int* in_sizes, int n_in,
                              void* d_out, int out_size, void* d_ws, size_t ws_size,
                              hipStream_t stream) {
    const float* x    = (const float*)d_in[0];
    const int*   ei   = (const int*)d_in[1];
    const int*   batch= (const int*)d_in[2];
    const float* W1   = (const float*)d_in[3];
    const float* b1   = (const float*)d_in[4];
    const float* W2   = (const float*)d_in[5];
    const float* b2   = (const float*)d_in[6];
    const float* Wl1  = (const float*)d_in[7];
    const float* bl1  = (const float*)d_in[8];
    const float* Wl2  = (const float*)d_in[9];
    const float* bl2  = (const float*)d_in[10];
    const float* Wl22 = (const float*)d_in[11];
    const float* bl22 = (const float*)d_in[12];
    const float* Wl23 = (const float*)d_in[13];
    const float* bl23 = (const float*)d_in[14];
    const float* Wl3  = (const float*)d_in[15];
    const float* bl3  = (const float*)d_in[16];

    const int D = 128;
    const int N = in_sizes[0] / D;            // 50000
    const int E = in_sizes[1] / 2;            // 800000
    const int G = out_size / D;               // 256
    const int H = in_sizes[10];               // 1024
    const int Mpad = ((N + 127) / 128) * 128; // 50048
    const int* row = ei;
    const int* col = ei + E;
    float* out = (float*)d_out;

    char* ws = (char*)d_ws;
    auto alloc = [&](size_t bytes) -> void* {
        void* p = (void*)ws;
        ws += (bytes + 255) & ~(size_t)255;
        return p;
    };
    int*    indeg  = (int*)alloc((size_t)N * 4);
    int*    cursor = (int*)alloc((size_t)N * 4);
    int*    offs   = (int*)alloc((size_t)(N + 1) * 4);
    int*    adj    = (int*)alloc((size_t)E * 4);
    float*  dinv   = (float*)alloc((size_t)N * 4);
    int*    bsum   = (int*)alloc((size_t)1024 * 4);
    // node-GEMM weights (transposed+split)
    ushort* W1th   = (ushort*)alloc((size_t)256 * 128 * 2);
    ushort* W1tl   = (ushort*)alloc((size_t)256 * 128 * 2);
    ushort* W2th   = (ushort*)alloc((size_t)128 * 256 * 2);
    ushort* W2tl   = (ushort*)alloc((size_t)128 * 256 * 2);
    // MLP weights (transposed+split)
    ushort* Tl1h  = (ushort*)alloc((size_t)128 * 128 * 2);
    ushort* Tl1l  = (ushort*)alloc((size_t)128 * 128 * 2);
    ushort* Tl2h  = (ushort*)alloc((size_t)H * 128 * 2);
    ushort* Tl2l  = (ushort*)alloc((size_t)H * 128 * 2);
    ushort* Tl22h = (ushort*)alloc((size_t)H * H * 2);
    ushort* Tl22l = (ushort*)alloc((size_t)H * H * 2);
    ushort* Tl23h = (ushort*)alloc((size_t)H * H * 2);
    ushort* Tl23l = (ushort*)alloc((size_t)H * H * 2);
    ushort* Tl3h  = (ushort*)alloc((size_t)128 * H * 2);
    ushort* Tl3l  = (ushort*)alloc((size_t)128 * H * 2);
    // activations
    ushort* yh     = (ushort*)alloc((size_t)Mpad * 128 * 2);   // 12.8 MB
    ushort* yl     = (ushort*)alloc((size_t)Mpad * 128 * 2);   // 12.8 MB
    ushort* out1h  = (ushort*)alloc((size_t)Mpad * 256 * 2);   // 25.6 MB
    ushort* out1l  = (ushort*)alloc((size_t)Mpad * 256 * 2);   // 25.6 MB
    ushort* gh     = (ushort*)alloc((size_t)G * 128 * 2);
    ushort* gl     = (ushort*)alloc((size_t)G * 128 * 2);
    ushort* a1h    = (ushort*)alloc((size_t)G * 128 * 2);
    ushort* a1l    = (ushort*)alloc((size_t)G * 128 * 2);
    ushort* a2h    = (ushort*)alloc((size_t)G * H * 2);
    ushort* a2l    = (ushort*)alloc((size_t)G * H * 2);
    ushort* a3h    = (ushort*)alloc((size_t)G * H * 2);
    ushort* a3l    = (ushort*)alloc((size_t)G * H * 2);
    ushort* a4h    = (ushort*)alloc((size_t)G * H * 2);
    ushort* a4l    = (ushort*)alloc((size_t)G * H * 2);

    // aliases (lifetimes disjoint):
    float* hs2 = (float*)yh;     // [N,128] f32 spans yh+yl (both dead after gemm1)
    float* y   = (float*)out1h;  // [N,128] f32 spans out1h (dead after gemm2)

    // ---- CSR build + normalization ----
    hipMemsetAsync(indeg, 0, (size_t)N * 4, stream);
    hipMemsetAsync(cursor, 0, (size_t)N * 4, stream);
    count_deg_kernel<<<(E + 255) / 256, 256, 0, stream>>>(col, E, indeg);
    {
        int nb = (N + 1023) / 1024;   // 49
        scan_p1_kernel<<<nb, 256, 0, stream>>>(indeg, bsum, N);
        scan_p2_kernel<<<1, 1024, 0, stream>>>(bsum, nb);
        scan_p3_kernel<<<nb, 256, 0, stream>>>(indeg, bsum, offs, dinv, N);
    }
    fill_adj_kernel<<<(E + 255) / 256, 256, 0, stream>>>(row, col, offs, cursor, adj, E);

    // ---- weight transpose + split ----
    tsplit_kernel<<<dim3(128 / 64, 256 / 64), 256, 0, stream>>>(W1, W1th, W1tl, 128, 256);
    tsplit_kernel<<<dim3(256 / 64, 128 / 64), 256, 0, stream>>>(W2, W2th, W2tl, 256, 128);
    tsplit_kernel<<<dim3(128 / 64, 128 / 64), 256, 0, stream>>>(Wl1, Tl1h, Tl1l, 128, 128);
    tsplit_kernel<<<dim3(128 / 64, H / 64), 256, 0, stream>>>(Wl2, Tl2h, Tl2l, 128, H);
    tsplit_kernel<<<dim3(H / 64, H / 64), 256, 0, stream>>>(Wl22, Tl22h, Tl22l, H, H);
    tsplit_kernel<<<dim3(H / 64, H / 64), 256, 0, stream>>>(Wl23, Tl23h, Tl23l, H, H);
    tsplit_kernel<<<dim3(H / 64, 128 / 64), 256, 0, stream>>>(Wl3, Tl3h, Tl3l, H, 128);

    // ---- Layer 1: aggregate (dinv folded) -> bf16 split ----
    aggregate128_kernel<1><<<(N + 3) / 4, 256, 0, stream>>>(
        x, offs, adj, dinv, nullptr, nullptr, yh, yl, N);
    {   // out1(h,l) = split(relu(y @ W1 + b1))   [N,256]
        dim3 grid(Mpad / 128, 256 / 128);
        gemm_bf16x3_kernel<128, 1><<<grid, 256, 0, stream>>>(
            yh, yl, W1th, W1tl, b1, nullptr, nullptr, out1h, out1l, N, 256, 128);
    }

    // ---- Layer 2: hs2 = dinv * (out1 @ W2); aggregate + b2 + relu ----
    {
        dim3 grid(Mpad / 128, 1);
        gemm_bf16x3_kernel<128, 0><<<grid, 256, 0, stream>>>(
            out1h, out1l, W2th, W2tl, nullptr, dinv, hs2, nullptr, nullptr, N, 128, 256);
    }
    aggregate128_kernel<0><<<(N + 3) / 4, 256, 0, stream>>>(
        hs2, offs, adj, dinv, b2, y, nullptr, nullptr, N);

    // ---- global mean pool (emits bf16 hi/lo) ----
    pool_kernel<<<G, 256, 0, stream>>>(y, batch, gh, gl, N);

    // ---- MLP (all MFMA bf16x3, BM=64) ----
    {   // a1 = relu(g @ Wl1 + bl1)        [G,128]
        dim3 grid(G / 64, 128 / 64);
        gemm_bf16x3_kernel<64, 1><<<grid, 256, 0, stream>>>(
            gh, gl, Tl1h, Tl1l, bl1, nullptr, nullptr, a1h, a1l, G, 128, 128);
    }
    {   // a2 = relu(a1 @ Wl2 + bl2)       [G,1024]
        dim3 grid(G / 64, H / 64);
        gemm_bf16x3_kernel<64, 1><<<grid, 256, 0, stream>>>(
            a1h, a1l, Tl2h, Tl2l, bl2, nullptr, nullptr, a2h, a2l, G, H, 128);
    }
    {   // a3 = relu(a2 @ Wl22 + bl22)     [G,1024]
        dim3 grid(G / 64, H / 64);
        gemm_bf16x3_kernel<64, 1><<<grid, 256, 0, stream>>>(
            a2h, a2l, Tl22h, Tl22l, bl22, nullptr, nullptr, a3h, a3l, G, H, H);
    }
    {   // a4 = relu(a3 @ Wl23 + bl23)     [G,1024]
        dim3 grid(G / 64, H / 64);
        gemm_bf16x3_kernel<64, 1><<<grid, 256, 0, stream>>>(
            a3h, a3l, Tl23h, Tl23l, bl23, nullptr, nullptr, a4h, a4l, G, H, H);
    }
    {   // out = a4 @ Wl3 + bl3            [G,128] f32
        dim3 grid(G / 64, 128 / 64);
        gemm_bf16x3_kernel<64, 2><<<grid, 256, 0, stream>>>(
            a4h, a4l, Tl3h, Tl3l, bl3, nullptr, out, nullptr, nullptr, G, 128, H);
    }
}

// Round 6
// 361.818 us; speedup vs baseline: 1.9028x; 1.0799x over previous
//
#include <hip/hip_runtime.h>

// ---------------------------------------------------------------------------
// PatternEncoder: 2x GCNConv -> global_mean_pool -> 5-layer MLP
// N=50000, E=800000, D=128, G=256, H=1024
// All GEMMs use MFMA bf16x3 (C = Ah@Bh + Ah@Bl + Al@Bh), rel err ~1e-5.
// Aggregation: pull-based CSR, 2 nodes/wave (float4/lane), 8-deep batching.
// MLP K=1024 layers use split-K (f32 atomics) + fused finish epilogue.
// ---------------------------------------------------------------------------

typedef __attribute__((ext_vector_type(8))) short bf16x8;
typedef __attribute__((ext_vector_type(8))) ushort u16x8;
typedef __attribute__((ext_vector_type(4))) float f32x4;

__device__ __forceinline__ ushort f2bf(float f) {
    unsigned u = __float_as_uint(f);
    unsigned r = (u + 0x7FFFu + ((u >> 16) & 1u)) >> 16;
    return (ushort)r;
}
__device__ __forceinline__ float bf2f(ushort h) {
    return __uint_as_float(((unsigned)h) << 16);
}

// ------------------------------ CSR build ---------------------------------

__global__ void count_deg_kernel(const int* __restrict__ col, int E,
                                 int* __restrict__ indeg) {
    int i = blockIdx.x * blockDim.x + threadIdx.x;
    if (i < E) atomicAdd(&indeg[col[i]], 1);
}

// phase 1: per-block (1024 elems) partial sums
__global__ void scan_p1_kernel(const int* __restrict__ indeg, int* __restrict__ bsum,
                               int N) {
    __shared__ int sm[256];
    int b = blockIdx.x, tid = threadIdx.x;
    int base = b * 1024 + tid * 4;
    int sum = 0;
    if (base + 4 <= N) {
        int4 v = *(const int4*)(indeg + base);
        sum = v.x + v.y + v.z + v.w;
    } else {
        for (int i = 0; i < 4; ++i) if (base + i < N) sum += indeg[base + i];
    }
    sm[tid] = sum;
    __syncthreads();
    for (int off = 128; off > 0; off >>= 1) {
        if (tid < off) sm[tid] += sm[tid + off];
        __syncthreads();
    }
    if (tid == 0) bsum[b] = sm[0];
}

// phase 2: single block scans the <=1024 block sums (exclusive, in place)
__global__ void scan_p2_kernel(int* __restrict__ bsum, int nb) {
    __shared__ int sm[1024];
    int tid = threadIdx.x;
    int v = (tid < nb) ? bsum[tid] : 0;
    sm[tid] = v;
    __syncthreads();
    int val = v;
    for (int off = 1; off < 1024; off <<= 1) {
        int t = (tid >= off) ? sm[tid - off] : 0;
        __syncthreads();
        val += t;
        sm[tid] = val;
        __syncthreads();
    }
    if (tid < nb) bsum[tid] = val - v;
}

// phase 3: per-block exclusive scan; writes offs, dinv, and offs[N]
__global__ void scan_p3_kernel(const int* __restrict__ indeg, const int* __restrict__ bsum,
                               int* __restrict__ offs, float* __restrict__ dinv, int N) {
    __shared__ int sm[256];
    int b = blockIdx.x, tid = threadIdx.x;
    int base = b * 1024 + tid * 4;
    int d[4];
    int sum = 0;
    if (base + 4 <= N) {
        int4 v = *(const int4*)(indeg + base);
        d[0] = v.x; d[1] = v.y; d[2] = v.z; d[3] = v.w;
        sum = v.x + v.y + v.z + v.w;
    } else {
#pragma unroll
        for (int i = 0; i < 4; ++i) {
            d[i] = (base + i < N) ? indeg[base + i] : 0;
            sum += d[i];
        }
    }
    sm[tid] = sum;
    __syncthreads();
    int val = sum;
    for (int off = 1; off < 256; off <<= 1) {
        int t = (tid >= off) ? sm[tid - off] : 0;
        __syncthreads();
        val += t;
        sm[tid] = val;
        __syncthreads();
    }
    int prefix = bsum[b] + val - sum;
#pragma unroll
    for (int i = 0; i < 4; ++i) {
        int idx = base + i;
        if (idx < N) {
            offs[idx] = prefix;
            dinv[idx] = rsqrtf((float)(d[i] + 1));
            prefix += d[i];
            if (idx == N - 1) offs[N] = prefix;
        }
    }
}

// cursor pre-initialized to offs (d2d copy): single atomic per edge
__global__ void fill_adj_kernel(const int* __restrict__ row, const int* __restrict__ col,
                                int* __restrict__ cursor, int* __restrict__ adj, int E) {
    int e = blockIdx.x * blockDim.x + threadIdx.x;
    if (e < E) {
        int pos = atomicAdd(&cursor[col[e]], 1);
        adj[pos] = row[e];
    }
}

// ---------------- weight transpose+split (all 7 weights, one launch) --------
struct TJobs {
    const float* W[7];
    ushort* Th[7];
    ushort* Tl[7];
    int K[7];
    int Nn[7];
    int off[8];
};

__global__ __launch_bounds__(256) void tsplit_all_kernel(TJobs jobs) {
    __shared__ float sm[64][65];
    int b = blockIdx.x;
    int j = 0;
#pragma unroll
    for (int t = 1; t < 7; ++t) if (b >= jobs.off[t]) j = t;
    int local = b - jobs.off[j];
    int K = jobs.K[j], Nn = jobs.Nn[j];
    int kt = K >> 6;
    int k0 = (local % kt) * 64, n0 = (local / kt) * 64;
    const float* W = jobs.W[j];
    ushort* Th = jobs.Th[j];
    ushort* Tl = jobs.Tl[j];

    int tid = threadIdx.x;
    int r = tid >> 2, cq = tid & 3;
#pragma unroll
    for (int i = 0; i < 4; ++i) {
        float4 v = *(const float4*)(W + (size_t)(k0 + r) * Nn + n0 + cq * 16 + i * 4);
        sm[r][cq * 16 + i * 4 + 0] = v.x;
        sm[r][cq * 16 + i * 4 + 1] = v.y;
        sm[r][cq * 16 + i * 4 + 2] = v.z;
        sm[r][cq * 16 + i * 4 + 3] = v.w;
    }
    __syncthreads();
    int n = tid >> 2, kq = tid & 3;
    ushort h[16], l[16];
#pragma unroll
    for (int i = 0; i < 16; ++i) {
        float v = sm[kq * 16 + i][n];
        h[i] = f2bf(v);
        l[i] = f2bf(v - bf2f(h[i]));
    }
    size_t o = (size_t)(n0 + n) * K + k0 + kq * 16;
    *(u16x8*)(&Th[o]) = *(u16x8*)&h[0];
    *(u16x8*)(&Th[o + 8]) = *(u16x8*)&h[8];
    *(u16x8*)(&Tl[o]) = *(u16x8*)&l[0];
    *(u16x8*)(&Tl[o + 8]) = *(u16x8*)&l[8];
}

// ------------------------------ aggregation --------------------------------
// 2 nodes per wave: lanes 0-31 node A, lanes 32-63 node B; float4 per lane.
// MODE 1 (layer 1): out = dinv[i]*(sum dinv[src]*x[src] + dinv[i]*x[i]); bf16 hi/lo
// MODE 0 (layer 2): out = relu(dinv[i]*(sum hs[src] + hs[i]) + bias);    f32
template<int MODE>
__global__ void aggregate128_kernel(const float* __restrict__ hs,
                                    const int* __restrict__ offs,
                                    const int* __restrict__ adj,
                                    const float* __restrict__ dinv,
                                    const float* __restrict__ bias,
                                    float* __restrict__ outf,
                                    ushort* __restrict__ outh, ushort* __restrict__ outl,
                                    int N) {
    int wv = (blockIdx.x * blockDim.x + threadIdx.x) >> 6;
    int lane = threadIdx.x & 63;
    int half = lane >> 5, l32 = lane & 31;
    int node = wv * 2 + half;
    bool active = node < N;
    int nd = active ? node : N - 1;
    const float4* base = (const float4*)hs;
    float dself = dinv[nd];
    float4 a = base[(size_t)nd * 32 + l32];
    float ax, ay, az, aw;
    if (MODE == 1) { ax = a.x * dself; ay = a.y * dself; az = a.z * dself; aw = a.w * dself; }
    else           { ax = a.x;         ay = a.y;         az = a.z;         aw = a.w; }
    int s = offs[nd];
    int deg = active ? (offs[nd + 1] - s) : 0;
    int mx = max(deg, __shfl_xor(deg, 32));
    for (int j = 0; j < mx; j += 8) {
        int idx[8]; float w[8];
#pragma unroll
        for (int k = 0; k < 8; ++k) {
            int jj = j + k;
            bool valid = jj < deg;
            int ld = adj[s + (valid ? jj : 0)];
            idx[k] = valid ? ld : 0;
            w[k] = valid ? 1.f : 0.f;
        }
        float4 v[8];
#pragma unroll
        for (int k = 0; k < 8; ++k) v[k] = base[(size_t)idx[k] * 32 + l32];
        if (MODE == 1) {
#pragma unroll
            for (int k = 0; k < 8; ++k) w[k] *= dinv[idx[k]];
        }
#pragma unroll
        for (int k = 0; k < 8; ++k) {
            ax = fmaf(w[k], v[k].x, ax);
            ay = fmaf(w[k], v[k].y, ay);
            az = fmaf(w[k], v[k].z, az);
            aw = fmaf(w[k], v[k].w, aw);
        }
    }
    ax *= dself; ay *= dself; az *= dself; aw *= dself;
    if (!active) return;
    if (MODE == 0) {
        float4 b = ((const float4*)bias)[l32];
        ax = fmaxf(ax + b.x, 0.f); ay = fmaxf(ay + b.y, 0.f);
        az = fmaxf(az + b.z, 0.f); aw = fmaxf(aw + b.w, 0.f);
        ((float4*)outf)[(size_t)node * 32 + l32] = make_float4(ax, ay, az, aw);
    } else {
        ushort h0 = f2bf(ax), h1 = f2bf(ay), h2 = f2bf(az), h3 = f2bf(aw);
        uint2 hv = make_uint2((unsigned)h0 | ((unsigned)h1 << 16),
                              (unsigned)h2 | ((unsigned)h3 << 16));
        ushort l0 = f2bf(ax - bf2f(h0)), l1 = f2bf(ay - bf2f(h1));
        ushort l2 = f2bf(az - bf2f(h2)), l3 = f2bf(aw - bf2f(h3));
        uint2 lv = make_uint2((unsigned)l0 | ((unsigned)l1 << 16),
                              (unsigned)l2 | ((unsigned)l3 << 16));
        ((uint2*)outh)[(size_t)node * 32 + l32] = hv;
        ((uint2*)outl)[(size_t)node * 32 + l32] = lv;
    }
}

// --------------------------- MFMA bf16x3 GEMM ------------------------------
// C[M,N] = A[M,K] @ B[K,N]; A = (Ah,Al) bf16 [M,K]; B = (Bth,Btl) bf16 [N][K].
// Tile BMxBN, BK=32, 4 waves (2x2). kChunk enables split-K via blockIdx.z.
// EPI 0: v *= rowscale[row]; f32 out
// EPI 1: v = relu(v + bias[col]); bf16 hi/lo out
// EPI 3: atomicAdd into pre-zeroed f32 Cf (split-K partial)
#define SWZ(r) (((r) >> 1) & 3)

template<int BM, int BN, int EPI>
__global__ __launch_bounds__(256) void gemm_bf16x3_kernel(
        const ushort* __restrict__ Ah, const ushort* __restrict__ Al,
        const ushort* __restrict__ Bth, const ushort* __restrict__ Btl,
        const float* __restrict__ bias, const float* __restrict__ rowscale,
        float* __restrict__ Cf, ushort* __restrict__ Ch, ushort* __restrict__ Cl,
        int M, int N, int K, int kChunk) {
    constexpr int WMm = BM / 2, WMn = BN / 2;
    constexpr int FRm = WMm / 16, FRn = WMn / 16;
    __shared__ __align__(16) ushort lds[(2 * BM + 2 * BN) * 32];
    const int tbB[4] = {0, BM * 64, 2 * BM * 64, (2 * BM + BN) * 64};  // byte offsets

    const int tid = threadIdx.x;
    const int w = tid >> 6, lane = tid & 63;
    const int wr = w >> 1, wc = w & 1;
    const int bm = blockIdx.x * BM, bn = blockIdx.y * BN;
    const int k0 = blockIdx.z * kChunk;
    int k1 = k0 + kChunk; if (k1 > K) k1 = K;

    const ushort* srcs[4] = {
        Ah  + (size_t)bm * K, Al  + (size_t)bm * K,
        Bth + (size_t)bn * K, Btl + (size_t)bn * K };

    f32x4 acc[FRm][FRn];
#pragma unroll
    for (int i = 0; i < FRm; ++i)
#pragma unroll
        for (int j = 0; j < FRn; ++j) acc[i][j] = (f32x4)0.f;

    const int sq = lane >> 4, r16 = lane & 15;

    for (int kk = k0; kk < k1; kk += 32) {
#pragma unroll
        for (int t = 0; t < 4; ++t) {
            const int rows = (t < 2) ? BM : BN;
            const int nv = rows / 64;
#pragma unroll
            for (int v = 0; v < nv; ++v) {
                int chunk = v * 4 + w;
                int rowi = chunk * 16 + (lane >> 2);
                int u = lane & 3;
                int colk = kk + 8 * (u ^ SWZ(rowi));
                const ushort* g = srcs[t] + (size_t)rowi * K + colk;
                ushort* lp = (ushort*)((char*)lds + tbB[t] + chunk * 16 * 64);
                __builtin_amdgcn_global_load_lds(
                    (const __attribute__((address_space(1))) void*)g,
                    (__attribute__((address_space(3))) void*)lp, 16, 0, 0);
            }
        }
        __syncthreads();

        bf16x8 ah[FRm], al[FRm], bh[FRn], bl[FRn];
#pragma unroll
        for (int f = 0; f < FRm; ++f) {
            int ra = wr * WMm + f * 16 + r16;
            int oa = ra * 64 + 16 * (sq ^ SWZ(ra));
            ah[f] = *(const bf16x8*)((const char*)lds + tbB[0] + oa);
            al[f] = *(const bf16x8*)((const char*)lds + tbB[1] + oa);
        }
#pragma unroll
        for (int f = 0; f < FRn; ++f) {
            int rb = wc * WMn + f * 16 + r16;
            int ob = rb * 64 + 16 * (sq ^ SWZ(rb));
            bh[f] = *(const bf16x8*)((const char*)lds + tbB[2] + ob);
            bl[f] = *(const bf16x8*)((const char*)lds + tbB[3] + ob);
        }

#pragma unroll
        for (int i = 0; i < FRm; ++i)
#pragma unroll
            for (int j = 0; j < FRn; ++j) {
                acc[i][j] = __builtin_amdgcn_mfma_f32_16x16x32_bf16(ah[i], bh[j], acc[i][j], 0, 0, 0);
                acc[i][j] = __builtin_amdgcn_mfma_f32_16x16x32_bf16(ah[i], bl[j], acc[i][j], 0, 0, 0);
                acc[i][j] = __builtin_amdgcn_mfma_f32_16x16x32_bf16(al[i], bh[j], acc[i][j], 0, 0, 0);
            }
        __syncthreads();
    }

    // C/D layout: col=lane&15, row=(lane>>4)*4+reg (m89-verified)
    const int q4 = lane >> 4;
#pragma unroll
    for (int i = 0; i < FRm; ++i) {
        int row0 = bm + wr * WMm + i * 16 + q4 * 4;
        if (row0 >= M) continue;
#pragma unroll
        for (int j = 0; j < FRn; ++j) {
            int colc = bn + wc * WMn + j * 16 + r16;
            if (EPI == 1) {
                float bv = bias[colc];
#pragma unroll
                for (int r = 0; r < 4; ++r) {
                    float v = fmaxf(acc[i][j][r] + bv, 0.f);
                    ushort h = f2bf(v);
                    ushort lo = f2bf(v - bf2f(h));
                    size_t o = (size_t)(row0 + r) * N + colc;
                    Ch[o] = h; Cl[o] = lo;
                }
            } else if (EPI == 0) {
#pragma unroll
                for (int r = 0; r < 4; ++r) {
                    float v = acc[i][j][r] * rowscale[row0 + r];
                    Cf[(size_t)(row0 + r) * N + colc] = v;
                }
            } else {
#pragma unroll
                for (int r = 0; r < 4; ++r)
                    atomicAdd(&Cf[(size_t)(row0 + r) * N + colc], acc[i][j][r]);
            }
        }
    }
}

// split-K finish: v = acc + bias[col]; optional relu; write bf16 pair or f32
__global__ void finish_kernel(const float* __restrict__ acc, const float* __restrict__ bias,
                              float* __restrict__ outf, ushort* __restrict__ outh,
                              ushort* __restrict__ outl, int total, int Ncols, int doRelu) {
    int idx = blockIdx.x * blockDim.x + threadIdx.x;
    if (idx >= total) return;
    float v = acc[idx] + bias[idx & (Ncols - 1)];
    if (doRelu) v = fmaxf(v, 0.f);
    if (outh) {
        ushort h = f2bf(v);
        outh[idx] = h;
        outl[idx] = f2bf(v - bf2f(h));
    } else {
        outf[idx] = v;
    }
}

// ------------------------------- pooling -----------------------------------
__global__ void pool_kernel(const float* __restrict__ feats, const int* __restrict__ batch,
                            ushort* __restrict__ gh, ushort* __restrict__ gl, int N) {
    __shared__ float sm[256];
    int gid = blockIdx.x;
    int lo = 0, hi = N;
    while (lo < hi) { int m = (lo + hi) >> 1; if (batch[m] < gid) lo = m + 1; else hi = m; }
    int start = lo;
    lo = start; hi = N;
    while (lo < hi) { int m = (lo + hi) >> 1; if (batch[m] < gid + 1) lo = m + 1; else hi = m; }
    int end = lo;
    int tid = threadIdx.x;
    int f = tid & 127, half = tid >> 7;
    float acc = 0.f;
    for (int i = start + half; i < end; i += 2) acc += feats[(size_t)i * 128 + f];
    sm[tid] = acc;
    __syncthreads();
    if (half == 0) {
        acc += sm[tid + 128];
        int cnt = end - start; if (cnt < 1) cnt = 1;
        float m = acc / (float)cnt;
        ushort h = f2bf(m);
        gh[gid * 128 + f] = h;
        gl[gid * 128 + f] = f2bf(m - bf2f(h));
    }
}

// ---------------------------------------------------------------------------

extern "C" void kernel_launch(void* const* d_in, const int* in_sizes, int n_in,
                              void* d_out, int out_size, void* d_ws, size_t ws_size,
                              hipStream_t stream) {
    const float* x    = (const float*)d_in[0];
    const int*   ei   = (const int*)d_in[1];
    const int*   batch= (const int*)d_in[2];
    const float* W1   = (const float*)d_in[3];
    const float* b1   = (const float*)d_in[4];
    const float* W2   = (const float*)d_in[5];
    const float* b2   = (const float*)d_in[6];
    const float* Wl1  = (const float*)d_in[7];
    const float* bl1  = (const float*)d_in[8];
    const float* Wl2  = (const float*)d_in[9];
    const float* bl2  = (const float*)d_in[10];
    const float* Wl22 = (const float*)d_in[11];
    const float* bl22 = (const float*)d_in[12];
    const float* Wl23 = (const float*)d_in[13];
    const float* bl23 = (const float*)d_in[14];
    const float* Wl3  = (const float*)d_in[15];
    const float* bl3  = (const float*)d_in[16];

    const int D = 128;
    const int N = in_sizes[0] / D;            // 50000
    const int E = in_sizes[1] / 2;            // 800000
    const int G = out_size / D;               // 256
    const int H = in_sizes[10];               // 1024
    const int Mpad = ((N + 127) / 128) * 128; // 50048
    const int* row = ei;
    const int* col = ei + E;
    float* out = (float*)d_out;

    char* ws = (char*)d_ws;
    auto alloc = [&](size_t bytes) -> void* {
        void* p = (void*)ws;
        ws += (bytes + 255) & ~(size_t)255;
        return p;
    };
    int*    indeg  = (int*)alloc((size_t)N * 4);
    int*    cursor = (int*)alloc((size_t)N * 4);
    int*    offs   = (int*)alloc((size_t)(N + 1) * 4);
    int*    adj    = (int*)alloc((size_t)E * 4);
    float*  dinv   = (float*)alloc((size_t)N * 4);
    int*    bsum   = (int*)alloc((size_t)1024 * 4);
    // node-GEMM weights (transposed+split)
    ushort* W1th   = (ushort*)alloc((size_t)256 * 128 * 2);
    ushort* W1tl   = (ushort*)alloc((size_t)256 * 128 * 2);
    ushort* W2th   = (ushort*)alloc((size_t)128 * 256 * 2);
    ushort* W2tl   = (ushort*)alloc((size_t)128 * 256 * 2);
    // MLP weights (transposed+split)
    ushort* Tl1h  = (ushort*)alloc((size_t)128 * 128 * 2);
    ushort* Tl1l  = (ushort*)alloc((size_t)128 * 128 * 2);
    ushort* Tl2h  = (ushort*)alloc((size_t)H * 128 * 2);
    ushort* Tl2l  = (ushort*)alloc((size_t)H * 128 * 2);
    ushort* Tl22h = (ushort*)alloc((size_t)H * H * 2);
    ushort* Tl22l = (ushort*)alloc((size_t)H * H * 2);
    ushort* Tl23h = (ushort*)alloc((size_t)H * H * 2);
    ushort* Tl23l = (ushort*)alloc((size_t)H * H * 2);
    ushort* Tl3h  = (ushort*)alloc((size_t)128 * H * 2);
    ushort* Tl3l  = (ushort*)alloc((size_t)128 * H * 2);
    // activations
    ushort* yh     = (ushort*)alloc((size_t)Mpad * 128 * 2);   // 12.8 MB
    ushort* yl     = (ushort*)alloc((size_t)Mpad * 128 * 2);   // 12.8 MB
    ushort* out1h  = (ushort*)alloc((size_t)Mpad * 256 * 2);   // 25.6 MB
    ushort* out1l  = (ushort*)alloc((size_t)Mpad * 256 * 2);   // 25.6 MB
    ushort* gh     = (ushort*)alloc((size_t)G * 128 * 2);
    ushort* gl     = (ushort*)alloc((size_t)G * 128 * 2);
    ushort* a1h    = (ushort*)alloc((size_t)G * 128 * 2);
    ushort* a1l    = (ushort*)alloc((size_t)G * 128 * 2);
    ushort* a2h    = (ushort*)alloc((size_t)G * H * 2);
    ushort* a2l    = (ushort*)alloc((size_t)G * H * 2);
    ushort* a3h    = (ushort*)alloc((size_t)G * H * 2);
    ushort* a3l    = (ushort*)alloc((size_t)G * H * 2);
    ushort* a4h    = (ushort*)alloc((size_t)G * H * 2);
    ushort* a4l    = (ushort*)alloc((size_t)G * H * 2);
    float*  accb   = (float*)alloc((size_t)G * H * 4);         // split-K accumulator
    float*  accf   = (float*)alloc((size_t)G * 128 * 4);       // final-layer accumulator

    // aliases (lifetimes disjoint):
    float* hs2 = (float*)yh;     // [N,128] f32 spans yh+yl (both dead after gemm1)
    float* y   = (float*)out1h;  // [N,128] f32 spans out1h (dead after gemm2)

    // ---- CSR build + normalization ----
    hipMemsetAsync(indeg, 0, (size_t)N * 4, stream);
    count_deg_kernel<<<(E + 255) / 256, 256, 0, stream>>>(col, E, indeg);
    {
        int nb = (N + 1023) / 1024;   // 49
        scan_p1_kernel<<<nb, 256, 0, stream>>>(indeg, bsum, N);
        scan_p2_kernel<<<1, 1024, 0, stream>>>(bsum, nb);
        scan_p3_kernel<<<nb, 256, 0, stream>>>(indeg, bsum, offs, dinv, N);
    }
    hipMemcpyAsync(cursor, offs, (size_t)N * 4, hipMemcpyDeviceToDevice, stream);
    fill_adj_kernel<<<(E + 255) / 256, 256, 0, stream>>>(row, col, cursor, adj, E);

    // ---- weight transpose + split (single fused launch) ----
    {
        TJobs jb;
        const float* Ws[7]  = {W1, W2, Wl1, Wl2, Wl22, Wl23, Wl3};
        ushort* Ths[7]      = {W1th, W2th, Tl1h, Tl2h, Tl22h, Tl23h, Tl3h};
        ushort* Tls[7]      = {W1tl, W2tl, Tl1l, Tl2l, Tl22l, Tl23l, Tl3l};
        int Ks[7]           = {128, 256, 128, 128, H, H, H};
        int Nns[7]          = {256, 128, 128, H, H, H, 128};
        int off = 0;
        for (int j = 0; j < 7; ++j) {
            jb.W[j] = Ws[j]; jb.Th[j] = Ths[j]; jb.Tl[j] = Tls[j];
            jb.K[j] = Ks[j]; jb.Nn[j] = Nns[j];
            jb.off[j] = off;
            off += (Ks[j] / 64) * (Nns[j] / 64);
        }
        jb.off[7] = off;
        tsplit_all_kernel<<<off, 256, 0, stream>>>(jb);
    }

    // ---- Layer 1: aggregate (dinv folded) -> bf16 split ----
    aggregate128_kernel<1><<<(N + 7) / 8, 256, 0, stream>>>(
        x, offs, adj, dinv, nullptr, nullptr, yh, yl, N);
    {   // out1(h,l) = split(relu(y @ W1 + b1))   [N,256]
        dim3 grid(Mpad / 128, 2);
        gemm_bf16x3_kernel<128, 128, 1><<<grid, 256, 0, stream>>>(
            yh, yl, W1th, W1tl, b1, nullptr, nullptr, out1h, out1l, N, 256, 128, 128);
    }

    // ---- Layer 2: hs2 = dinv * (out1 @ W2); aggregate + b2 + relu ----
    {
        dim3 grid(Mpad / 128, 2);
        gemm_bf16x3_kernel<128, 64, 0><<<grid, 256, 0, stream>>>(
            out1h, out1l, W2th, W2tl, nullptr, dinv, hs2, nullptr, nullptr, N, 128, 256, 256);
    }
    aggregate128_kernel<0><<<(N + 7) / 8, 256, 0, stream>>>(
        hs2, offs, adj, dinv, b2, y, nullptr, nullptr, N);

    // ---- global mean pool (emits bf16 hi/lo) ----
    pool_kernel<<<G, 256, 0, stream>>>(y, batch, gh, gl, N);

    // ---- MLP ----
    {   // a1 = relu(g @ Wl1 + bl1)        [G,128]
        dim3 grid(G / 64, 2);
        gemm_bf16x3_kernel<64, 64, 1><<<grid, 256, 0, stream>>>(
            gh, gl, Tl1h, Tl1l, bl1, nullptr, nullptr, a1h, a1l, G, 128, 128, 128);
    }
    {   // a2 = relu(a1 @ Wl2 + bl2)       [G,1024]
        dim3 grid(G / 64, H / 64);
        gemm_bf16x3_kernel<64, 64, 1><<<grid, 256, 0, stream>>>(
            a1h, a1l, Tl2h, Tl2l, bl2, nullptr, nullptr, a2h, a2l, G, H, 128, 128);
    }
    {   // a3 = relu(a2 @ Wl22 + bl22)     [G,1024]  split-K x4
        hipMemsetAsync(accb, 0, (size_t)G * H * 4, stream);
        dim3 grid(G / 64, H / 64, 4);
        gemm_bf16x3_kernel<64, 64, 3><<<grid, 256, 0, stream>>>(
            a2h, a2l, Tl22h, Tl22l, nullptr, nullptr, accb, nullptr, nullptr, G, H, H, 256);
        finish_kernel<<<(G * H + 255) / 256, 256, 0, stream>>>(
            accb, bl22, nullptr, a3h, a3l, G * H, H, 1);
    }
    {   // a4 = relu(a3 @ Wl23 + bl23)     [G,1024]  split-K x4
        hipMemsetAsync(accb, 0, (size_t)G * H * 4, stream);
        dim3 grid(G / 64, H / 64, 4);
        gemm_bf16x3_kernel<64, 64, 3><<<grid, 256, 0, stream>>>(
            a3h, a3l, Tl23h, Tl23l, nullptr, nullptr, accb, nullptr, nullptr, G, H, H, 256);
        finish_kernel<<<(G * H + 255) / 256, 256, 0, stream>>>(
            accb, bl23, nullptr, a4h, a4l, G * H, H, 1);
    }
    {   // out = a4 @ Wl3 + bl3            [G,128]   split-K x8, f32
        hipMemsetAsync(accf, 0, (size_t)G * 128 * 4, stream);
        dim3 grid(G / 64, 2, 8);
        gemm_bf16x3_kernel<64, 64, 3><<<grid, 256, 0, stream>>>(
            a4h, a4l, Tl3h, Tl3l, nullptr, nullptr, accf, nullptr, nullptr, G, 128, H, 128);
        finish_kernel<<<(G * 128 + 255) / 256, 256, 0, stream>>>(
            accf, bl3, out, nullptr, nullptr, G * 128, 128, 0);
    }
}

// Round 7
// 343.612 us; speedup vs baseline: 2.0036x; 1.0530x over previous
//
#include <hip/hip_runtime.h>

// ---------------------------------------------------------------------------
// PatternEncoder: 2x GCNConv -> global_mean_pool -> 5-layer MLP
// N=50000, E=800000, D=128, G=256, H=1024
// All GEMMs use MFMA bf16x3 (C = Ah@Bh + Ah@Bl + Al@Bh), rel err ~1e-5.
// Round 7: gemm1+gemm2 fused into gcn_mid_kernel (T1 kept in LDS, saves
// 102 MB of HBM traffic); aggregates use 16-deep neighbor batching.
// ---------------------------------------------------------------------------

typedef __attribute__((ext_vector_type(8))) short bf16x8;
typedef __attribute__((ext_vector_type(8))) ushort u16x8;
typedef __attribute__((ext_vector_type(4))) float f32x4;

__device__ __forceinline__ ushort f2bf(float f) {
    unsigned u = __float_as_uint(f);
    unsigned r = (u + 0x7FFFu + ((u >> 16) & 1u)) >> 16;
    return (ushort)r;
}
__device__ __forceinline__ float bf2f(ushort h) {
    return __uint_as_float(((unsigned)h) << 16);
}
__device__ __forceinline__ void gload16(const ushort* g, ushort* l) {
    __builtin_amdgcn_global_load_lds(
        (const __attribute__((address_space(1))) void*)g,
        (__attribute__((address_space(3))) void*)l, 16, 0, 0);
}

#define SWZ(r) (((r) >> 1) & 3)

// ------------------------------ CSR build ---------------------------------

__global__ void count_deg_kernel(const int* __restrict__ col, int E,
                                 int* __restrict__ indeg) {
    int i = blockIdx.x * blockDim.x + threadIdx.x;
    if (i < E) atomicAdd(&indeg[col[i]], 1);
}

__global__ void scan_p1_kernel(const int* __restrict__ indeg, int* __restrict__ bsum,
                               int N) {
    __shared__ int sm[256];
    int b = blockIdx.x, tid = threadIdx.x;
    int base = b * 1024 + tid * 4;
    int sum = 0;
    if (base + 4 <= N) {
        int4 v = *(const int4*)(indeg + base);
        sum = v.x + v.y + v.z + v.w;
    } else {
        for (int i = 0; i < 4; ++i) if (base + i < N) sum += indeg[base + i];
    }
    sm[tid] = sum;
    __syncthreads();
    for (int off = 128; off > 0; off >>= 1) {
        if (tid < off) sm[tid] += sm[tid + off];
        __syncthreads();
    }
    if (tid == 0) bsum[b] = sm[0];
}

__global__ void scan_p2_kernel(int* __restrict__ bsum, int nb) {
    __shared__ int sm[1024];
    int tid = threadIdx.x;
    int v = (tid < nb) ? bsum[tid] : 0;
    sm[tid] = v;
    __syncthreads();
    int val = v;
    for (int off = 1; off < 1024; off <<= 1) {
        int t = (tid >= off) ? sm[tid - off] : 0;
        __syncthreads();
        val += t;
        sm[tid] = val;
        __syncthreads();
    }
    if (tid < nb) bsum[tid] = val - v;
}

__global__ void scan_p3_kernel(const int* __restrict__ indeg, const int* __restrict__ bsum,
                               int* __restrict__ offs, float* __restrict__ dinv, int N) {
    __shared__ int sm[256];
    int b = blockIdx.x, tid = threadIdx.x;
    int base = b * 1024 + tid * 4;
    int d[4];
    int sum = 0;
    if (base + 4 <= N) {
        int4 v = *(const int4*)(indeg + base);
        d[0] = v.x; d[1] = v.y; d[2] = v.z; d[3] = v.w;
        sum = v.x + v.y + v.z + v.w;
    } else {
#pragma unroll
        for (int i = 0; i < 4; ++i) {
            d[i] = (base + i < N) ? indeg[base + i] : 0;
            sum += d[i];
        }
    }
    sm[tid] = sum;
    __syncthreads();
    int val = sum;
    for (int off = 1; off < 256; off <<= 1) {
        int t = (tid >= off) ? sm[tid - off] : 0;
        __syncthreads();
        val += t;
        sm[tid] = val;
        __syncthreads();
    }
    int prefix = bsum[b] + val - sum;
#pragma unroll
    for (int i = 0; i < 4; ++i) {
        int idx = base + i;
        if (idx < N) {
            offs[idx] = prefix;
            dinv[idx] = rsqrtf((float)(d[i] + 1));
            prefix += d[i];
            if (idx == N - 1) offs[N] = prefix;
        }
    }
}

__global__ void fill_adj_kernel(const int* __restrict__ row, const int* __restrict__ col,
                                int* __restrict__ cursor, int* __restrict__ adj, int E) {
    int e = blockIdx.x * blockDim.x + threadIdx.x;
    if (e < E) {
        int pos = atomicAdd(&cursor[col[e]], 1);
        adj[pos] = row[e];
    }
}

// ---------------- weight transpose+split (all 7 weights, one launch) --------
struct TJobs {
    const float* W[7];
    ushort* Th[7];
    ushort* Tl[7];
    int K[7];
    int Nn[7];
    int off[8];
};

__global__ __launch_bounds__(256) void tsplit_all_kernel(TJobs jobs) {
    __shared__ float sm[64][65];
    int b = blockIdx.x;
    int j = 0;
#pragma unroll
    for (int t = 1; t < 7; ++t) if (b >= jobs.off[t]) j = t;
    int local = b - jobs.off[j];
    int K = jobs.K[j], Nn = jobs.Nn[j];
    int kt = K >> 6;
    int k0 = (local % kt) * 64, n0 = (local / kt) * 64;
    const float* W = jobs.W[j];
    ushort* Th = jobs.Th[j];
    ushort* Tl = jobs.Tl[j];

    int tid = threadIdx.x;
    int r = tid >> 2, cq = tid & 3;
#pragma unroll
    for (int i = 0; i < 4; ++i) {
        float4 v = *(const float4*)(W + (size_t)(k0 + r) * Nn + n0 + cq * 16 + i * 4);
        sm[r][cq * 16 + i * 4 + 0] = v.x;
        sm[r][cq * 16 + i * 4 + 1] = v.y;
        sm[r][cq * 16 + i * 4 + 2] = v.z;
        sm[r][cq * 16 + i * 4 + 3] = v.w;
    }
    __syncthreads();
    int n = tid >> 2, kq = tid & 3;
    ushort h[16], l[16];
#pragma unroll
    for (int i = 0; i < 16; ++i) {
        float v = sm[kq * 16 + i][n];
        h[i] = f2bf(v);
        l[i] = f2bf(v - bf2f(h[i]));
    }
    size_t o = (size_t)(n0 + n) * K + k0 + kq * 16;
    *(u16x8*)(&Th[o]) = *(u16x8*)&h[0];
    *(u16x8*)(&Th[o + 8]) = *(u16x8*)&h[8];
    *(u16x8*)(&Tl[o]) = *(u16x8*)&l[0];
    *(u16x8*)(&Tl[o + 8]) = *(u16x8*)&l[8];
}

// ------------------------------ aggregation --------------------------------
// 2 nodes per wave: lanes 0-31 node A, lanes 32-63 node B; float4 per lane;
// 16-deep neighbor batching for memory-level parallelism.
// MODE 1 (layer 1): out = dinv[i]*(sum dinv[src]*x[src] + dinv[i]*x[i]); bf16 hi/lo
// MODE 0 (layer 2): out = relu(dinv[i]*(sum hs[src] + hs[i]) + bias);    f32
template<int MODE>
__global__ void aggregate128_kernel(const float* __restrict__ hs,
                                    const int* __restrict__ offs,
                                    const int* __restrict__ adj,
                                    const float* __restrict__ dinv,
                                    const float* __restrict__ bias,
                                    float* __restrict__ outf,
                                    ushort* __restrict__ outh, ushort* __restrict__ outl,
                                    int N) {
    int wv = (blockIdx.x * blockDim.x + threadIdx.x) >> 6;
    int lane = threadIdx.x & 63;
    int half = lane >> 5, l32 = lane & 31;
    int node = wv * 2 + half;
    bool active = node < N;
    int nd = active ? node : N - 1;
    const float4* base = (const float4*)hs;
    float dself = dinv[nd];
    float4 a = base[(size_t)nd * 32 + l32];
    float ax, ay, az, aw;
    if (MODE == 1) { ax = a.x * dself; ay = a.y * dself; az = a.z * dself; aw = a.w * dself; }
    else           { ax = a.x;         ay = a.y;         az = a.z;         aw = a.w; }
    int s = offs[nd];
    int deg = active ? (offs[nd + 1] - s) : 0;
    int mx = max(deg, __shfl_xor(deg, 32));
    for (int j = 0; j < mx; j += 16) {
        int idx[16]; float wgt[16];
#pragma unroll
        for (int k = 0; k < 16; ++k) {
            int jj = j + k;
            bool valid = jj < deg;
            int ld = adj[s + (valid ? jj : 0)];
            idx[k] = valid ? ld : 0;
            wgt[k] = valid ? 1.f : 0.f;
        }
        float4 v[16];
#pragma unroll
        for (int k = 0; k < 16; ++k) v[k] = base[(size_t)idx[k] * 32 + l32];
        if (MODE == 1) {
#pragma unroll
            for (int k = 0; k < 16; ++k) wgt[k] *= dinv[idx[k]];
        }
#pragma unroll
        for (int k = 0; k < 16; ++k) {
            ax = fmaf(wgt[k], v[k].x, ax);
            ay = fmaf(wgt[k], v[k].y, ay);
            az = fmaf(wgt[k], v[k].z, az);
            aw = fmaf(wgt[k], v[k].w, aw);
        }
    }
    ax *= dself; ay *= dself; az *= dself; aw *= dself;
    if (!active) return;
    if (MODE == 0) {
        float4 b = ((const float4*)bias)[l32];
        ax = fmaxf(ax + b.x, 0.f); ay = fmaxf(ay + b.y, 0.f);
        az = fmaxf(az + b.z, 0.f); aw = fmaxf(aw + b.w, 0.f);
        ((float4*)outf)[(size_t)node * 32 + l32] = make_float4(ax, ay, az, aw);
    } else {
        ushort h0 = f2bf(ax), h1 = f2bf(ay), h2 = f2bf(az), h3 = f2bf(aw);
        uint2 hv = make_uint2((unsigned)h0 | ((unsigned)h1 << 16),
                              (unsigned)h2 | ((unsigned)h3 << 16));
        ushort l0 = f2bf(ax - bf2f(h0)), l1 = f2bf(ay - bf2f(h1));
        ushort l2 = f2bf(az - bf2f(h2)), l3 = f2bf(aw - bf2f(h3));
        uint2 lv = make_uint2((unsigned)l0 | ((unsigned)l1 << 16),
                              (unsigned)l2 | ((unsigned)l3 << 16));
        ((uint2*)outh)[(size_t)node * 32 + l32] = hv;
        ((uint2*)outl)[(size_t)node * 32 + l32] = lv;
    }
}

// --------------------- fused node GEMMs (layer1 + layer2) -------------------
// Per 128-row block:
//   stage 1: T1 = relu(y @ W1 + b1)        [128,256]  (bf16 hi/lo -> LDS)
//   stage 2: hs2 = dinv * (T1 @ W2)        [128,128]  (f32 -> global)
// 512 threads = 8 waves. LDS: T1 128KB (first 48KB aliased as stage-1 staging)
// + 16KB stage-2 staging = 144KB -> 1 block/CU.
__global__ __launch_bounds__(512) void gcn_mid_kernel(
        const ushort* __restrict__ Ah, const ushort* __restrict__ Al,   // y [Mpad][128]
        const ushort* __restrict__ B1h, const ushort* __restrict__ B1l, // W1t [256][128]
        const ushort* __restrict__ B2h, const ushort* __restrict__ B2l, // W2t [128][256]
        const float* __restrict__ bias1, const float* __restrict__ dinv,
        float* __restrict__ outf, int M) {
    __shared__ __align__(16) ushort t1f[2 * 128 * 256 + 2 * 128 * 32];  // 144 KB
    // layout (ushort offsets):
    //   t1 plane h: 0..32767   plane l: 32768..65535
    //   stage-1 staging (aliased over t1): Ah 0, Al 4096, B1h 8192, B1l 16384
    //   stage-2 staging: B2h 65536, B2l 69632
    const int tid = threadIdx.x;
    const int w = tid >> 6, lane = tid & 63;
    const int bm = blockIdx.x * 128;
    const int sq = lane >> 4, r16 = lane & 15;

    // ---------------- stage 1: 2x4 wave grid, wave tile 64x64
    {
        const int wr = w >> 2, wc = w & 3;
        f32x4 acc1[4][4];
#pragma unroll
        for (int i = 0; i < 4; ++i)
#pragma unroll
            for (int j = 0; j < 4; ++j) acc1[i][j] = (f32x4)0.f;

        for (int kk = 0; kk < 128; kk += 32) {
            {   // stage A tiles [128][32] (1 issue/wave/plane)
                int rowi = w * 16 + (lane >> 2);
                int u = lane & 3;
                int colk = kk + 8 * (u ^ SWZ(rowi));
                gload16(Ah + (size_t)(bm + rowi) * 128 + colk, t1f + w * 512);
                gload16(Al + (size_t)(bm + rowi) * 128 + colk, t1f + 4096 + w * 512);
            }
#pragma unroll
            for (int v = 0; v < 2; ++v) {  // stage B tiles [256][32] (2 issues/wave/plane)
                int chunk = v * 8 + w;
                int rowi = chunk * 16 + (lane >> 2);
                int u = lane & 3;
                int colk = kk + 8 * (u ^ SWZ(rowi));
                gload16(B1h + (size_t)rowi * 128 + colk, t1f + 8192 + chunk * 512);
                gload16(B1l + (size_t)rowi * 128 + colk, t1f + 16384 + chunk * 512);
            }
            __syncthreads();

            bf16x8 ah[4], al[4], bh[4], bl[4];
#pragma unroll
            for (int f = 0; f < 4; ++f) {
                int ra = wr * 64 + f * 16 + r16;
                int oa = ra * 32 + 8 * (sq ^ SWZ(ra));
                ah[f] = *(const bf16x8*)(t1f + oa);
                al[f] = *(const bf16x8*)(t1f + 4096 + oa);
                int rb = wc * 64 + f * 16 + r16;
                int ob = rb * 32 + 8 * (sq ^ SWZ(rb));
                bh[f] = *(const bf16x8*)(t1f + 8192 + ob);
                bl[f] = *(const bf16x8*)(t1f + 16384 + ob);
            }
#pragma unroll
            for (int i = 0; i < 4; ++i)
#pragma unroll
                for (int j = 0; j < 4; ++j) {
                    acc1[i][j] = __builtin_amdgcn_mfma_f32_16x16x32_bf16(ah[i], bh[j], acc1[i][j], 0, 0, 0);
                    acc1[i][j] = __builtin_amdgcn_mfma_f32_16x16x32_bf16(ah[i], bl[j], acc1[i][j], 0, 0, 0);
                    acc1[i][j] = __builtin_amdgcn_mfma_f32_16x16x32_bf16(al[i], bh[j], acc1[i][j], 0, 0, 0);
                }
            __syncthreads();
        }

        // epilogue 1: bias+relu, split to bf16 hi/lo, scatter into swizzled T1
        const int q4 = lane >> 4;
#pragma unroll
        for (int j = 0; j < 4; ++j) {
            int col = wc * 64 + j * 16 + r16;
            float bv = bias1[col];
            int cslot = col >> 3, coff = col & 7;
#pragma unroll
            for (int i = 0; i < 4; ++i) {
                int rowb = wr * 64 + i * 16 + q4 * 4;
#pragma unroll
                for (int r = 0; r < 4; ++r) {
                    int rowt = rowb + r;
                    float v = fmaxf(acc1[i][j][r] + bv, 0.f);
                    ushort h = f2bf(v);
                    ushort lo = f2bf(v - bf2f(h));
                    int a = rowt * 256 + (((cslot ^ (rowt & 7)) << 3) + coff);
                    t1f[a] = h;
                    t1f[32768 + a] = lo;
                }
            }
        }
        // no explicit barrier: stage-2 loop's first __syncthreads covers it
    }

    // ---------------- stage 2: 4x2 wave grid, wave tile 32x64, K=256
    {
        const int wr2 = w >> 1, wc2 = w & 1;
        const int q4 = lane >> 4;
        f32x4 acc2[2][4];
#pragma unroll
        for (int i = 0; i < 2; ++i)
#pragma unroll
            for (int j = 0; j < 4; ++j) acc2[i][j] = (f32x4)0.f;

        for (int kk = 0; kk < 256; kk += 32) {
            {   // stage B2 tiles [128][32] (1 issue/wave/plane)
                int rowi = w * 16 + (lane >> 2);
                int u = lane & 3;
                int colk = kk + 8 * (u ^ SWZ(rowi));
                gload16(B2h + (size_t)rowi * 256 + colk, t1f + 65536 + w * 512);
                gload16(B2l + (size_t)rowi * 256 + colk, t1f + 69632 + w * 512);
            }
            __syncthreads();

            bf16x8 a2h[2], a2l[2], b2h[4], b2l[4];
#pragma unroll
            for (int f = 0; f < 2; ++f) {
                int ra = wr2 * 32 + f * 16 + r16;
                int k0 = kk + sq * 8;
                int ao = ra * 256 + (((k0 >> 3) ^ (ra & 7)) << 3);
                a2h[f] = *(const bf16x8*)(t1f + ao);
                a2l[f] = *(const bf16x8*)(t1f + 32768 + ao);
            }
#pragma unroll
            for (int f = 0; f < 4; ++f) {
                int rb = wc2 * 64 + f * 16 + r16;
                int ob = rb * 32 + 8 * (sq ^ SWZ(rb));
                b2h[f] = *(const bf16x8*)(t1f + 65536 + ob);
                b2l[f] = *(const bf16x8*)(t1f + 69632 + ob);
            }
#pragma unroll
            for (int i = 0; i < 2; ++i)
#pragma unroll
                for (int j = 0; j < 4; ++j) {
                    acc2[i][j] = __builtin_amdgcn_mfma_f32_16x16x32_bf16(a2h[i], b2h[j], acc2[i][j], 0, 0, 0);
                    acc2[i][j] = __builtin_amdgcn_mfma_f32_16x16x32_bf16(a2h[i], b2l[j], acc2[i][j], 0, 0, 0);
                    acc2[i][j] = __builtin_amdgcn_mfma_f32_16x16x32_bf16(a2l[i], b2h[j], acc2[i][j], 0, 0, 0);
                }
            __syncthreads();
        }

        // epilogue 2: dinv row scale, f32 out
#pragma unroll
        for (int i = 0; i < 2; ++i) {
            int row0 = bm + wr2 * 32 + i * 16 + q4 * 4;
            if (row0 >= M) continue;
#pragma unroll
            for (int j = 0; j < 4; ++j) {
                int col = wc2 * 64 + j * 16 + r16;
#pragma unroll
                for (int r = 0; r < 4; ++r)
                    outf[(size_t)(row0 + r) * 128 + col] = acc2[i][j][r] * dinv[row0 + r];
            }
        }
    }
}

// --------------------------- MFMA bf16x3 GEMM (MLP) -------------------------
template<int BM, int BN, int EPI>
__global__ __launch_bounds__(256) void gemm_bf16x3_kernel(
        const ushort* __restrict__ Ah, const ushort* __restrict__ Al,
        const ushort* __restrict__ Bth, const ushort* __restrict__ Btl,
        const float* __restrict__ bias, const float* __restrict__ rowscale,
        float* __restrict__ Cf, ushort* __restrict__ Ch, ushort* __restrict__ Cl,
        int M, int N, int K, int kChunk) {
    constexpr int WMm = BM / 2, WMn = BN / 2;
    constexpr int FRm = WMm / 16, FRn = WMn / 16;
    __shared__ __align__(16) ushort lds[(2 * BM + 2 * BN) * 32];
    const int tbB[4] = {0, BM * 64, 2 * BM * 64, (2 * BM + BN) * 64};

    const int tid = threadIdx.x;
    const int w = tid >> 6, lane = tid & 63;
    const int wr = w >> 1, wc = w & 1;
    const int bm = blockIdx.x * BM, bn = blockIdx.y * BN;
    const int k0 = blockIdx.z * kChunk;
    int k1 = k0 + kChunk; if (k1 > K) k1 = K;

    const ushort* srcs[4] = {
        Ah  + (size_t)bm * K, Al  + (size_t)bm * K,
        Bth + (size_t)bn * K, Btl + (size_t)bn * K };

    f32x4 acc[FRm][FRn];
#pragma unroll
    for (int i = 0; i < FRm; ++i)
#pragma unroll
        for (int j = 0; j < FRn; ++j) acc[i][j] = (f32x4)0.f;

    const int sq = lane >> 4, r16 = lane & 15;

    for (int kk = k0; kk < k1; kk += 32) {
#pragma unroll
        for (int t = 0; t < 4; ++t) {
            const int rows = (t < 2) ? BM : BN;
            const int nv = rows / 64;
#pragma unroll
            for (int v = 0; v < nv; ++v) {
                int chunk = v * 4 + w;
                int rowi = chunk * 16 + (lane >> 2);
                int u = lane & 3;
                int colk = kk + 8 * (u ^ SWZ(rowi));
                const ushort* g = srcs[t] + (size_t)rowi * K + colk;
                ushort* lp = (ushort*)((char*)lds + tbB[t] + chunk * 16 * 64);
                gload16(g, lp);
            }
        }
        __syncthreads();

        bf16x8 ah[FRm], al[FRm], bh[FRn], bl[FRn];
#pragma unroll
        for (int f = 0; f < FRm; ++f) {
            int ra = wr * WMm + f * 16 + r16;
            int oa = ra * 64 + 16 * (sq ^ SWZ(ra));
            ah[f] = *(const bf16x8*)((const char*)lds + tbB[0] + oa);
            al[f] = *(const bf16x8*)((const char*)lds + tbB[1] + oa);
        }
#pragma unroll
        for (int f = 0; f < FRn; ++f) {
            int rb = wc * WMn + f * 16 + r16;
            int ob = rb * 64 + 16 * (sq ^ SWZ(rb));
            bh[f] = *(const bf16x8*)((const char*)lds + tbB[2] + ob);
            bl[f] = *(const bf16x8*)((const char*)lds + tbB[3] + ob);
        }

#pragma unroll
        for (int i = 0; i < FRm; ++i)
#pragma unroll
            for (int j = 0; j < FRn; ++j) {
                acc[i][j] = __builtin_amdgcn_mfma_f32_16x16x32_bf16(ah[i], bh[j], acc[i][j], 0, 0, 0);
                acc[i][j] = __builtin_amdgcn_mfma_f32_16x16x32_bf16(ah[i], bl[j], acc[i][j], 0, 0, 0);
                acc[i][j] = __builtin_amdgcn_mfma_f32_16x16x32_bf16(al[i], bh[j], acc[i][j], 0, 0, 0);
            }
        __syncthreads();
    }

    const int q4 = lane >> 4;
#pragma unroll
    for (int i = 0; i < FRm; ++i) {
        int row0 = bm + wr * WMm + i * 16 + q4 * 4;
        if (row0 >= M) continue;
#pragma unroll
        for (int j = 0; j < FRn; ++j) {
            int colc = bn + wc * WMn + j * 16 + r16;
            if (EPI == 1) {
                float bv = bias[colc];
#pragma unroll
                for (int r = 0; r < 4; ++r) {
                    float v = fmaxf(acc[i][j][r] + bv, 0.f);
                    ushort h = f2bf(v);
                    ushort lo = f2bf(v - bf2f(h));
                    size_t o = (size_t)(row0 + r) * N + colc;
                    Ch[o] = h; Cl[o] = lo;
                }
            } else if (EPI == 0) {
#pragma unroll
                for (int r = 0; r < 4; ++r) {
                    float v = acc[i][j][r] * rowscale[row0 + r];
                    Cf[(size_t)(row0 + r) * N + colc] = v;
                }
            } else {
#pragma unroll
                for (int r = 0; r < 4; ++r)
                    atomicAdd(&Cf[(size_t)(row0 + r) * N + colc], acc[i][j][r]);
            }
        }
    }
}

__global__ void finish_kernel(const float* __restrict__ acc, const float* __restrict__ bias,
                              float* __restrict__ outf, ushort* __restrict__ outh,
                              ushort* __restrict__ outl, int total, int Ncols, int doRelu) {
    int idx = blockIdx.x * blockDim.x + threadIdx.x;
    if (idx >= total) return;
    float v = acc[idx] + bias[idx & (Ncols - 1)];
    if (doRelu) v = fmaxf(v, 0.f);
    if (outh) {
        ushort h = f2bf(v);
        outh[idx] = h;
        outl[idx] = f2bf(v - bf2f(h));
    } else {
        outf[idx] = v;
    }
}

// ------------------------------- pooling -----------------------------------
__global__ void pool_kernel(const float* __restrict__ feats, const int* __restrict__ batch,
                            ushort* __restrict__ gh, ushort* __restrict__ gl, int N) {
    __shared__ float sm[256];
    int gid = blockIdx.x;
    int lo = 0, hi = N;
    while (lo < hi) { int m = (lo + hi) >> 1; if (batch[m] < gid) lo = m + 1; else hi = m; }
    int start = lo;
    lo = start; hi = N;
    while (lo < hi) { int m = (lo + hi) >> 1; if (batch[m] < gid + 1) lo = m + 1; else hi = m; }
    int end = lo;
    int tid = threadIdx.x;
    int f = tid & 127, half = tid >> 7;
    float acc = 0.f;
    for (int i = start + half; i < end; i += 2) acc += feats[(size_t)i * 128 + f];
    sm[tid] = acc;
    __syncthreads();
    if (half == 0) {
        acc += sm[tid + 128];
        int cnt = end - start; if (cnt < 1) cnt = 1;
        float m = acc / (float)cnt;
        ushort h = f2bf(m);
        gh[gid * 128 + f] = h;
        gl[gid * 128 + f] = f2bf(m - bf2f(h));
    }
}

// ---------------------------------------------------------------------------

extern "C" void kernel_launch(void* const* d_in, const int* in_sizes, int n_in,
                              void* d_out, int out_size, void* d_ws, size_t ws_size,
                              hipStream_t stream) {
    const float* x    = (const float*)d_in[0];
    const int*   ei   = (const int*)d_in[1];
    const int*   batch= (const int*)d_in[2];
    const float* W1   = (const float*)d_in[3];
    const float* b1   = (const float*)d_in[4];
    const float* W2   = (const float*)d_in[5];
    const float* b2   = (const float*)d_in[6];
    const float* Wl1  = (const float*)d_in[7];
    const float* bl1  = (const float*)d_in[8];
    const float* Wl2  = (const float*)d_in[9];
    const float* bl2  = (const float*)d_in[10];
    const float* Wl22 = (const float*)d_in[11];
    const float* bl22 = (const float*)d_in[12];
    const float* Wl23 = (const float*)d_in[13];
    const float* bl23 = (const float*)d_in[14];
    const float* Wl3  = (const float*)d_in[15];
    const float* bl3  = (const float*)d_in[16];

    const int D = 128;
    const int N = in_sizes[0] / D;            // 50000
    const int E = in_sizes[1] / 2;            // 800000
    const int G = out_size / D;               // 256
    const int H = in_sizes[10];               // 1024
    const int Mpad = ((N + 127) / 128) * 128; // 50048
    const int* row = ei;
    const int* col = ei + E;
    float* out = (float*)d_out;

    char* ws = (char*)d_ws;
    auto alloc = [&](size_t bytes) -> void* {
        void* p = (void*)ws;
        ws += (bytes + 255) & ~(size_t)255;
        return p;
    };
    int*    indeg  = (int*)alloc((size_t)N * 4);
    int*    cursor = (int*)alloc((size_t)N * 4);
    int*    offs   = (int*)alloc((size_t)(N + 1) * 4);
    int*    adj    = (int*)alloc((size_t)E * 4);
    float*  dinv   = (float*)alloc((size_t)N * 4);
    int*    bsum   = (int*)alloc((size_t)1024 * 4);
    // node-GEMM weights (transposed+split)
    ushort* W1th   = (ushort*)alloc((size_t)256 * 128 * 2);
    ushort* W1tl   = (ushort*)alloc((size_t)256 * 128 * 2);
    ushort* W2th   = (ushort*)alloc((size_t)128 * 256 * 2);
    ushort* W2tl   = (ushort*)alloc((size_t)128 * 256 * 2);
    // MLP weights (transposed+split)
    ushort* Tl1h  = (ushort*)alloc((size_t)128 * 128 * 2);
    ushort* Tl1l  = (ushort*)alloc((size_t)128 * 128 * 2);
    ushort* Tl2h  = (ushort*)alloc((size_t)H * 128 * 2);
    ushort* Tl2l  = (ushort*)alloc((size_t)H * 128 * 2);
    ushort* Tl22h = (ushort*)alloc((size_t)H * H * 2);
    ushort* Tl22l = (ushort*)alloc((size_t)H * H * 2);
    ushort* Tl23h = (ushort*)alloc((size_t)H * H * 2);
    ushort* Tl23l = (ushort*)alloc((size_t)H * H * 2);
    ushort* Tl3h  = (ushort*)alloc((size_t)128 * H * 2);
    ushort* Tl3l  = (ushort*)alloc((size_t)128 * H * 2);
    // activations
    ushort* yh     = (ushort*)alloc((size_t)Mpad * 128 * 2);   // agg1 out (bf16 hi)
    ushort* yl     = (ushort*)alloc((size_t)Mpad * 128 * 2);   // agg1 out (bf16 lo)
    float*  hs2    = (float*)alloc((size_t)Mpad * 128 * 4);    // gcn_mid out
    float*  yf     = (float*)alloc((size_t)Mpad * 128 * 4);    // agg2 out
    ushort* gh     = (ushort*)alloc((size_t)G * 128 * 2);
    ushort* gl     = (ushort*)alloc((size_t)G * 128 * 2);
    ushort* a1h    = (ushort*)alloc((size_t)G * 128 * 2);
    ushort* a1l    = (ushort*)alloc((size_t)G * 128 * 2);
    ushort* a2h    = (ushort*)alloc((size_t)G * H * 2);
    ushort* a2l    = (ushort*)alloc((size_t)G * H * 2);
    ushort* a3h    = (ushort*)alloc((size_t)G * H * 2);
    ushort* a3l    = (ushort*)alloc((size_t)G * H * 2);
    ushort* a4h    = (ushort*)alloc((size_t)G * H * 2);
    ushort* a4l    = (ushort*)alloc((size_t)G * H * 2);
    float*  accb   = (float*)alloc((size_t)G * H * 4);
    float*  accf   = (float*)alloc((size_t)G * 128 * 4);

    // ---- CSR build + normalization ----
    hipMemsetAsync(indeg, 0, (size_t)N * 4, stream);
    count_deg_kernel<<<(E + 255) / 256, 256, 0, stream>>>(col, E, indeg);
    {
        int nb = (N + 1023) / 1024;   // 49
        scan_p1_kernel<<<nb, 256, 0, stream>>>(indeg, bsum, N);
        scan_p2_kernel<<<1, 1024, 0, stream>>>(bsum, nb);
        scan_p3_kernel<<<nb, 256, 0, stream>>>(indeg, bsum, offs, dinv, N);
    }
    hipMemcpyAsync(cursor, offs, (size_t)N * 4, hipMemcpyDeviceToDevice, stream);
    fill_adj_kernel<<<(E + 255) / 256, 256, 0, stream>>>(row, col, cursor, adj, E);

    // ---- weight transpose + split (single fused launch) ----
    {
        TJobs jb;
        const float* Ws[7]  = {W1, W2, Wl1, Wl2, Wl22, Wl23, Wl3};
        ushort* Ths[7]      = {W1th, W2th, Tl1h, Tl2h, Tl22h, Tl23h, Tl3h};
        ushort* Tls[7]      = {W1tl, W2tl, Tl1l, Tl2l, Tl22l, Tl23l, Tl3l};
        int Ks[7]           = {128, 256, 128, 128, H, H, H};
        int Nns[7]          = {256, 128, 128, H, H, H, 128};
        int off = 0;
        for (int j = 0; j < 7; ++j) {
            jb.W[j] = Ws[j]; jb.Th[j] = Ths[j]; jb.Tl[j] = Tls[j];
            jb.K[j] = Ks[j]; jb.Nn[j] = Nns[j];
            jb.off[j] = off;
            off += (Ks[j] / 64) * (Nns[j] / 64);
        }
        jb.off[7] = off;
        tsplit_all_kernel<<<off, 256, 0, stream>>>(jb);
    }

    // ---- Layer 1 aggregate (dinv folded) -> bf16 split ----
    aggregate128_kernel<1><<<(N + 7) / 8, 256, 0, stream>>>(
        x, offs, adj, dinv, nullptr, nullptr, yh, yl, N);

    // ---- fused node GEMMs: hs2 = dinv * (relu(y@W1+b1) @ W2) ----
    gcn_mid_kernel<<<Mpad / 128, 512, 0, stream>>>(
        yh, yl, W1th, W1tl, W2th, W2tl, b1, dinv, hs2, N);

    // ---- Layer 2 aggregate + b2 + relu ----
    aggregate128_kernel<0><<<(N + 7) / 8, 256, 0, stream>>>(
        hs2, offs, adj, dinv, b2, yf, nullptr, nullptr, N);

    // ---- global mean pool (emits bf16 hi/lo) ----
    pool_kernel<<<G, 256, 0, stream>>>(yf, batch, gh, gl, N);

    // ---- MLP ----
    {   // a1 = relu(g @ Wl1 + bl1)        [G,128]
        dim3 grid(G / 64, 2);
        gemm_bf16x3_kernel<64, 64, 1><<<grid, 256, 0, stream>>>(
            gh, gl, Tl1h, Tl1l, bl1, nullptr, nullptr, a1h, a1l, G, 128, 128, 128);
    }
    {   // a2 = relu(a1 @ Wl2 + bl2)       [G,1024]
        dim3 grid(G / 64, H / 64);
        gemm_bf16x3_kernel<64, 64, 1><<<grid, 256, 0, stream>>>(
            a1h, a1l, Tl2h, Tl2l, bl2, nullptr, nullptr, a2h, a2l, G, H, 128, 128);
    }
    {   // a3 = relu(a2 @ Wl22 + bl22)     [G,1024]  split-K x4
        hipMemsetAsync(accb, 0, (size_t)G * H * 4, stream);
        dim3 grid(G / 64, H / 64, 4);
        gemm_bf16x3_kernel<64, 64, 3><<<grid, 256, 0, stream>>>(
            a2h, a2l, Tl22h, Tl22l, nullptr, nullptr, accb, nullptr, nullptr, G, H, H, 256);
        finish_kernel<<<(G * H + 255) / 256, 256, 0, stream>>>(
            accb, bl22, nullptr, a3h, a3l, G * H, H, 1);
    }
    {   // a4 = relu(a3 @ Wl23 + bl23)     [G,1024]  split-K x4
        hipMemsetAsync(accb, 0, (size_t)G * H * 4, stream);
        dim3 grid(G / 64, H / 64, 4);
        gemm_bf16x3_kernel<64, 64, 3><<<grid, 256, 0, stream>>>(
            a3h, a3l, Tl23h, Tl23l, nullptr, nullptr, accb, nullptr, nullptr, G, H, H, 256);
        finish_kernel<<<(G * H + 255) / 256, 256, 0, stream>>>(
            accb, bl23, nullptr, a4h, a4l, G * H, H, 1);
    }
    {   // out = a4 @ Wl3 + bl3            [G,128]   split-K x8, f32
        hipMemsetAsync(accf, 0, (size_t)G * 128 * 4, stream);
        dim3 grid(G / 64, 2, 8);
        gemm_bf16x3_kernel<64, 64, 3><<<grid, 256, 0, stream>>>(
            a4h, a4l, Tl3h, Tl3l, nullptr, nullptr, accf, nullptr, nullptr, G, 128, H, 128);
        finish_kernel<<<(G * 128 + 255) / 256, 256, 0, stream>>>(
            accf, bl3, out, nullptr, nullptr, G * 128, 128, 0);
    }
}